// Round 8
// baseline (20463.744 us; speedup 1.0000x reference)
//
#include <hip/hip_runtime.h>
#include <math.h>

static constexpr int NB  = 1024;
static constexpr int NS  = 100;
static constexpr int NH  = 128;
static constexpr int NTHR = 64;         // 1 wave per block
static constexpr int NBLK = NB / 2;     // 512 blocks, 2 batches per wave

static constexpr int OUT_MU = 0;
static constexpr int OUT_LV = NB * NS;
static constexpr int OUT_Z  = 2 * NB * NS;
static constexpr int OUT_TI = 3 * NB * NS;
static constexpr int OUT_LP = 4 * NB * NS;

#define NEGF (-3.4e38f)
#define WB() __builtin_amdgcn_wave_barrier()

// Fused 3-row x 2-batch f32 dot — per-accumulator fmaf chain k-ascending (v14 verbatim).
template<int C4>
__device__ __forceinline__ void dot2x3f(const float* __restrict__ wr0,
        const float* __restrict__ wr1, const float* __restrict__ wr2,
        const float* __restrict__ x0, const float* __restrict__ x1,
        float& r00, float& r01, float& r10, float& r11, float& r20, float& r21)
{
    const float4* W0 = reinterpret_cast<const float4*>(wr0);
    const float4* W1 = reinterpret_cast<const float4*>(wr1);
    const float4* W2 = reinterpret_cast<const float4*>(wr2);
    const float4* X0 = reinterpret_cast<const float4*>(x0);
    const float4* X1 = reinterpret_cast<const float4*>(x1);
    float a00 = 0.f, a01 = 0.f, a10 = 0.f, a11 = 0.f, a20 = 0.f, a21 = 0.f;
    #pragma unroll 4
    for (int c = 0; c < C4; ++c) {
        float4 u0 = W0[c], u1 = W1[c], u2 = W2[c];
        float4 v0 = X0[c], v1 = X1[c];
        a00 = fmaf(u0.x, v0.x, a00); a00 = fmaf(u0.y, v0.y, a00); a00 = fmaf(u0.z, v0.z, a00); a00 = fmaf(u0.w, v0.w, a00);
        a01 = fmaf(u0.x, v1.x, a01); a01 = fmaf(u0.y, v1.y, a01); a01 = fmaf(u0.z, v1.z, a01); a01 = fmaf(u0.w, v1.w, a01);
        a10 = fmaf(u1.x, v0.x, a10); a10 = fmaf(u1.y, v0.y, a10); a10 = fmaf(u1.z, v0.z, a10); a10 = fmaf(u1.w, v0.w, a10);
        a11 = fmaf(u1.x, v1.x, a11); a11 = fmaf(u1.y, v1.y, a11); a11 = fmaf(u1.z, v1.z, a11); a11 = fmaf(u1.w, v1.w, a11);
        a20 = fmaf(u2.x, v0.x, a20); a20 = fmaf(u2.y, v0.y, a20); a20 = fmaf(u2.z, v0.z, a20); a20 = fmaf(u2.w, v0.w, a20);
        a21 = fmaf(u2.x, v1.x, a21); a21 = fmaf(u2.y, v1.y, a21); a21 = fmaf(u2.z, v1.z, a21); a21 = fmaf(u2.w, v1.w, a21);
    }
    r00 = a00; r01 = a01; r10 = a10; r11 = a11; r20 = a20; r21 = a21;
}

// One weight row vs TWO LDS vectors — v14 verbatim chain (pfc1).
template<int C4>
__device__ __forceinline__ void dot2f(const float* __restrict__ w,
        const float* __restrict__ x0, const float* __restrict__ x1, float& r0, float& r1)
{
    const float4* W = reinterpret_cast<const float4*>(w);
    const float4* X0 = reinterpret_cast<const float4*>(x0);
    const float4* X1 = reinterpret_cast<const float4*>(x1);
    float a0 = 0.f, a1 = 0.f;
    #pragma unroll 8
    for (int c = 0; c < C4; ++c) {
        float4 u = W[c];
        float4 v0 = X0[c], v1 = X1[c];
        a0 = fmaf(u.x, v0.x, a0); a0 = fmaf(u.y, v0.y, a0); a0 = fmaf(u.z, v0.z, a0); a0 = fmaf(u.w, v0.w, a0);
        a1 = fmaf(u.x, v1.x, a1); a1 = fmaf(u.y, v1.y, a1); a1 = fmaf(u.z, v1.z, a1); a1 = fmaf(u.w, v1.w, a1);
    }
    r0 = a0; r1 = a1;
}

template<int C4>
__device__ __forceinline__ void dot1f(const float* __restrict__ w,
        const float* __restrict__ x0, float& r0)
{
    const float4* W = reinterpret_cast<const float4*>(w);
    const float4* X0 = reinterpret_cast<const float4*>(x0);
    float a0 = 0.f;
    #pragma unroll 8
    for (int c = 0; c < C4; ++c) {
        float4 u = W[c];
        float4 v0 = X0[c];
        a0 = fmaf(u.x, v0.x, a0); a0 = fmaf(u.y, v0.y, a0); a0 = fmaf(u.z, v0.z, a0); a0 = fmaf(u.w, v0.w, a0);
    }
    r0 = a0;
}

// f64-accum dot (mu/lv epilogue) — R9 verbatim.
template<int C4>
__device__ __forceinline__ double dotwd(const float* __restrict__ w, const float* __restrict__ x)
{
    const float4* W = reinterpret_cast<const float4*>(w);
    double a = 0.0;
    #pragma unroll 8
    for (int c = 0; c < C4; ++c) {
        float4 u = W[c];
        const float* p = x + 4 * c;
        a = fma((double)u.x, (double)p[0], a);
        a = fma((double)u.y, (double)p[1], a);
        a = fma((double)u.z, (double)p[2], a);
        a = fma((double)u.w, (double)p[3], a);
    }
    return a;
}

// GRU nonlinearity on register gate-partials — identical expression to gruc
// (pa[j]->pa0, pa[NH+j]->pa1, pa[2NH+j]->pa2).
__device__ __forceinline__ float grucr(const float* __restrict__ bih, const float* __restrict__ bhh,
        float pa0, float pa1, float pa2, float pb0, float pb1, float pb2, float hold, int j)
{
    double r = 1.0 / (1.0 + exp(-(((double)pa0 + (double)bih[j])      + ((double)pb0 + (double)bhh[j]))));
    double z = 1.0 / (1.0 + exp(-(((double)pa1 + (double)bih[NH + j]) + ((double)pb1 + (double)bhh[NH + j]))));
    double n = tanh(((double)pa2 + (double)bih[2*NH + j]) + r * ((double)pb2 + (double)bhh[2*NH + j]));
    return (float)((1.0 - z) * n + z * (double)hold);
}

// q half-chain (v14 verbatim): 4-acc f64 over 64 k for both batches, shared W loads.
__device__ __forceinline__ void qhalf(const float* __restrict__ col, int k0,
        const float* __restrict__ hA, const float* __restrict__ hB, double& r0, double& r1)
{
    double a00=0.0,a01=0.0,a02=0.0,a03=0.0;
    double a10=0.0,a11=0.0,a12=0.0,a13=0.0;
    #pragma unroll 8
    for (int k = 0; k < 64; k += 4) {
        float w0 = col[(size_t)(k0+k+0) * NH];
        float w1 = col[(size_t)(k0+k+1) * NH];
        float w2 = col[(size_t)(k0+k+2) * NH];
        float w3 = col[(size_t)(k0+k+3) * NH];
        float4 h0 = *reinterpret_cast<const float4*>(&hA[k0+k]);
        float4 h1v = *reinterpret_cast<const float4*>(&hB[k0+k]);
        a00 = fma((double)w0, (double)h0.x, a00);
        a01 = fma((double)w1, (double)h0.y, a01);
        a02 = fma((double)w2, (double)h0.z, a02);
        a03 = fma((double)w3, (double)h0.w, a03);
        a10 = fma((double)w0, (double)h1v.x, a10);
        a11 = fma((double)w1, (double)h1v.y, a11);
        a12 = fma((double)w2, (double)h1v.z, a12);
        a13 = fma((double)w3, (double)h1v.w, a13);
    }
    r0 = (a00+a01)+(a02+a03); r1 = (a10+a11)+(a12+a13);
}

// relu head (v14 verbatim chain; qh pre-combined like v14's s_qh).
__device__ __forceinline__ float relu_head(const double* __restrict__ qh,
        const double2* __restrict__ dA, const float* __restrict__ va, float c0v, float c1v)
{
    double c00 = (double)c0v, c10 = (double)c1v;
    double acc0=0.0,acc1=0.0,acc2=0.0,acc3=0.0;
    #pragma unroll 4
    for (int h = 0; h < NH; h += 4) {
        double2 A0=dA[h+0],A1=dA[h+1],A2=dA[h+2],A3=dA[h+3];
        double p0 = fma(c00,A0.x,fma(c10,A0.y,qh[h+0]));
        double p1 = fma(c00,A1.x,fma(c10,A1.y,qh[h+1]));
        double p2 = fma(c00,A2.x,fma(c10,A2.y,qh[h+2]));
        double p3 = fma(c00,A3.x,fma(c10,A3.y,qh[h+3]));
        acc0 = fma(fmax(p0,0.0),(double)va[h+0],acc0);
        acc1 = fma(fmax(p1,0.0),(double)va[h+1],acc1);
        acc2 = fma(fmax(p2,0.0),(double)va[h+2],acc2);
        acc3 = fma(fmax(p3,0.0),(double)va[h+3],acc3);
    }
    return (float)((acc0+acc1)+(acc2+acc3));
}

// tanh head (v14 verbatim chain).
__device__ __forceinline__ float tanh_head(const double* __restrict__ qh,
        const double2* __restrict__ dA, const float* __restrict__ vp, float c0v, float c1v)
{
    double c00 = (double)c0v, c10 = (double)c1v;
    double acc0=0.0,acc1=0.0,acc2=0.0,acc3=0.0;
    #pragma unroll 4
    for (int h = 0; h < NH; h += 4) {
        double2 A0=dA[h+0],A1=dA[h+1],A2=dA[h+2],A3=dA[h+3];
        double p0 = fma(c00,A0.x,fma(c10,A0.y,qh[h+0]));
        double p1 = fma(c00,A1.x,fma(c10,A1.y,qh[h+1]));
        double p2 = fma(c00,A2.x,fma(c10,A2.y,qh[h+2]));
        double p3 = fma(c00,A3.x,fma(c10,A3.y,qh[h+3]));
        acc0 = fma((double)tanhf((float)p0),(double)vp[h+0],acc0);
        acc1 = fma((double)tanhf((float)p1),(double)vp[h+1],acc1);
        acc2 = fma((double)tanhf((float)p2),(double)vp[h+2],acc2);
        acc3 = fma((double)tanhf((float)p3),(double)vp[h+3],acc3);
    }
    return (float)((acc0+acc1)+(acc2+acc3));
}

// context chain (v14 verbatim).
__device__ __forceinline__ float ctx_chain(const float* __restrict__ a,
        const float* __restrict__ c0, const float* __restrict__ c1,
        float w0, float w1, float bb)
{
    double a0=0.0,a1=0.0,a2=0.0,a3=0.0;
    #pragma unroll 5
    for (int s = 0; s < NS; s += 4) {
        float ih0 = fmaf(c0[s+0], w0, fmaf(c1[s+0], w1, bb));
        float ih1 = fmaf(c0[s+1], w0, fmaf(c1[s+1], w1, bb));
        float ih2 = fmaf(c0[s+2], w0, fmaf(c1[s+2], w1, bb));
        float ih3 = fmaf(c0[s+3], w0, fmaf(c1[s+3], w1, bb));
        a0 += (double)a[s+0] * (double)ih0;
        a1 += (double)a[s+1] * (double)ih1;
        a2 += (double)a[s+2] * (double)ih2;
        a3 += (double)a[s+3] * (double)ih3;
    }
    return (float)((a0+a1)+(a2+a3));
}

// unmasked wave softmax (v18-verified): max tree, exp, sum tree, normalize.
__device__ __forceinline__ void wave_softmax(float v1, float v2v, bool hasHi, float* __restrict__ aout)
{
    const int lane = threadIdx.x;
    float v2 = hasHi ? v2v : NEGF;
    float m = fmaxf(v1, v2);
    m = fmaxf(m, __shfl_xor(m, 32)); m = fmaxf(m, __shfl_xor(m, 16));
    m = fmaxf(m, __shfl_xor(m, 8));  m = fmaxf(m, __shfl_xor(m, 4));
    m = fmaxf(m, __shfl_xor(m, 2));  m = fmaxf(m, __shfl_xor(m, 1));
    float f1 = (float)exp((double)v1 - (double)m);
    float f2 = 0.f;
    if (hasHi) f2 = (float)exp((double)v2v - (double)m);
    double ps = (double)f1 + (double)f2;
    ps += __shfl_xor(ps, 32); ps += __shfl_xor(ps, 16);
    ps += __shfl_xor(ps, 8);  ps += __shfl_xor(ps, 4);
    ps += __shfl_xor(ps, 2);  ps += __shfl_xor(ps, 1);
    aout[lane] = (float)((double)f1 / ps);
    if (hasHi) aout[lane + 64] = (float)((double)f2 / ps);
}

// collapse-table chain (v14 verbatim).
__device__ __forceinline__ void collapse(const float* __restrict__ Wm, int jj,
        const float* __restrict__ wi0, const float* __restrict__ wi1, const float* __restrict__ bi,
        double2& dA, double& dAb)
{
    double a0 = 0.0, a1 = 0.0, ab = 0.0;
    for (int k = 0; k < NH; ++k) {
        double wv = (double)Wm[(size_t)k * NH + jj];
        a0 = fma((double)wi0[k], wv, a0);
        a1 = fma((double)wi1[k], wv, a1);
        ab = fma((double)bi[k],  wv, ab);
    }
    dA.x = a0; dA.y = a1; dAb = ab;
}

__global__ __launch_bounds__(NTHR) void vae_v19(
    const float* __restrict__ instance, const int* __restrict__ sol1,
    const int* __restrict__ sol2, const float* __restrict__ eps,
    const float* __restrict__ emb_i_W, const float* __restrict__ emb_i_b,
    const float* __restrict__ emb_r_W, const float* __restrict__ emb_r_b,
    const float* __restrict__ attn_W, const float* __restrict__ attn_v,
    const float* __restrict__ gru_Wih, const float* __restrict__ gru_Whh,
    const float* __restrict__ gru_bih, const float* __restrict__ gru_bhh,
    const float* __restrict__ grud_Wih, const float* __restrict__ grud_Whh,
    const float* __restrict__ grud_bih, const float* __restrict__ grud_bhh,
    const float* __restrict__ efc1_W, const float* __restrict__ efc1_b,
    const float* __restrict__ efc2_W, const float* __restrict__ efc2_b,
    const float* __restrict__ ptr_W, const float* __restrict__ ptr_v,
    const float* __restrict__ pfc1_W, const float* __restrict__ pfc1_b,
    const float* __restrict__ pfc2_W, const float* __restrict__ pfc2_b,
    float* __restrict__ out)
{
    __shared__ __align__(16) float s_x[2][360];
    __shared__ __align__(16) float s_h1[2][NH], s_h2[2][NH], s_fco[2][NH];
    __shared__ __align__(16) float s_fch[2][256];
    __shared__ double s_qh[2][NH];
    __shared__ double2 dAa[NH], dAp[NH];
    __shared__ double dAba[NH], dAbp[NH];
    __shared__ float s_a[2][NS];
    __shared__ float s_c0[2][NS], s_c1[2][NS], s_msk[2][NS];
    __shared__ float t_wi0[NH], t_wi1[NH], t_bi[NH];
    __shared__ float t_wr0[NH], t_wr1[NH], t_br[NH];
    __shared__ float t_va[NH], t_vp[NH];
    __shared__ float t_gbih[3*NH], t_gbhh[3*NH], t_dbih[3*NH], t_dbhh[3*NH];
    __shared__ float t_p1b[256], t_p2b[NH];
    __shared__ int s_sol1[2][NS], s_sol2[2][NS];

    const int lane = threadIdx.x;
    const int bbase = blockIdx.x * 2;
    const int jl = lane, jh = lane + 64;
    const bool hasHi = (jh < NS);   // lanes 0..35 own a second output row

    // ---------- init (single wave, no __syncthreads anywhere) ----------
    t_wi0[jl] = emb_i_W[2*jl]; t_wi1[jl] = emb_i_W[2*jl+1]; t_bi[jl] = emb_i_b[jl];
    t_wr0[jl] = emb_r_W[2*jl]; t_wr1[jl] = emb_r_W[2*jl+1]; t_br[jl] = emb_r_b[jl];
    t_wi0[jh] = emb_i_W[2*jh]; t_wi1[jh] = emb_i_W[2*jh+1]; t_bi[jh] = emb_i_b[jh];
    t_wr0[jh] = emb_r_W[2*jh]; t_wr1[jh] = emb_r_W[2*jh+1]; t_br[jh] = emb_r_b[jh];
    t_va[jl] = attn_v[jl]; t_va[jh] = attn_v[jh];
    t_vp[jl] = ptr_v[jl];  t_vp[jh] = ptr_v[jh];
    t_p2b[jl] = pfc2_b[jl]; t_p2b[jh] = pfc2_b[jh];
    for (int i = lane; i < 256; i += 64) t_p1b[i] = pfc1_b[i];
    for (int i = lane; i < 3*NH; i += 64) {
        t_gbih[i] = gru_bih[i]; t_gbhh[i] = gru_bhh[i];
        t_dbih[i] = grud_bih[i]; t_dbhh[i] = grud_bhh[i];
    }
    for (int i = lane; i < 2*NS; i += 64) {
        int g = i / NS, s = i - g*NS;
        s_c0[g][s] = instance[(size_t)((bbase+g)*NS + s)*2 + 0];
        s_c1[g][s] = instance[(size_t)((bbase+g)*NS + s)*2 + 1];
        s_sol1[g][s] = sol1[(bbase+g)*NS + s];
        s_sol2[g][s] = sol2[(bbase+g)*NS + s];
    }
    s_h1[0][jl] = 0.f; s_h1[0][jh] = 0.f; s_h1[1][jl] = 0.f; s_h1[1][jh] = 0.f;
    s_h2[0][jl] = 0.f; s_h2[0][jh] = 0.f; s_h2[1][jl] = 0.f; s_h2[1][jh] = 0.f;
    WB();
    collapse(attn_W, jl, t_wi0, t_wi1, t_bi, dAa[jl], dAba[jl]);
    collapse(attn_W, jh, t_wi0, t_wi1, t_bi, dAa[jh], dAba[jh]);
    collapse(ptr_W,  jl, t_wi0, t_wi1, t_bi, dAp[jl], dAbp[jl]);
    collapse(ptr_W,  jh, t_wi0, t_wi1, t_bi, dAp[jh], dAbp[jh]);
    {   // initial encoder ref_h
        int sp0 = s_sol1[0][0], sp1 = s_sol1[1][0];
        s_x[0][jl] = fmaf(s_c0[0][sp0], t_wr0[jl], fmaf(s_c1[0][sp0], t_wr1[jl], t_br[jl]));
        s_x[0][jh] = fmaf(s_c0[0][sp0], t_wr0[jh], fmaf(s_c1[0][sp0], t_wr1[jh], t_br[jh]));
        s_x[1][jl] = fmaf(s_c0[1][sp1], t_wr0[jl], fmaf(s_c1[1][sp1], t_wr1[jl], t_br[jl]));
        s_x[1][jh] = fmaf(s_c0[1][sp1], t_wr0[jh], fmaf(s_c1[1][sp1], t_wr1[jh], t_br[jh]));
    }
    WB();

    // ---------- encoder ----------
    for (int t = 1; t < NS; ++t) {
        // GRU1 dots (register-resident partials) + gruc1
        float xa,xb,xc,xd,xe,xf, ya,yb,yc,yd,ye,yf;
        dot2x3f<32>(gru_Wih + (size_t)jl*NH, gru_Wih + (size_t)(NH+jl)*NH,
                    gru_Wih + (size_t)(2*NH+jl)*NH, s_x[0], s_x[1], xa,xb,xc,xd,xe,xf);
        dot2x3f<32>(gru_Whh + (size_t)jl*NH, gru_Whh + (size_t)(NH+jl)*NH,
                    gru_Whh + (size_t)(2*NH+jl)*NH, s_h1[0], s_h1[1], ya,yb,yc,yd,ye,yf);
        float Xa,Xb,Xc,Xd,Xe,Xf, Ya,Yb,Yc,Yd,Ye,Yf;
        dot2x3f<32>(gru_Wih + (size_t)jh*NH, gru_Wih + (size_t)(NH+jh)*NH,
                    gru_Wih + (size_t)(2*NH+jh)*NH, s_x[0], s_x[1], Xa,Xb,Xc,Xd,Xe,Xf);
        dot2x3f<32>(gru_Whh + (size_t)jh*NH, gru_Whh + (size_t)(NH+jh)*NH,
                    gru_Whh + (size_t)(2*NH+jh)*NH, s_h1[0], s_h1[1], Ya,Yb,Yc,Yd,Ye,Yf);
        float n0l = grucr(t_gbih, t_gbhh, xa,xc,xe, ya,yc,ye, s_h1[0][jl], jl);
        float n1l = grucr(t_gbih, t_gbhh, xb,xd,xf, yb,yd,yf, s_h1[1][jl], jl);
        float n0h = grucr(t_gbih, t_gbhh, Xa,Xc,Xe, Ya,Yc,Ye, s_h1[0][jh], jh);
        float n1h = grucr(t_gbih, t_gbhh, Xb,Xd,Xf, Yb,Yd,Yf, s_h1[1][jh], jh);
        s_h1[0][jl] = n0l; s_h1[1][jl] = n1l; s_h1[0][jh] = n0h; s_h1[1][jh] = n1h;
        WB();
        // q (attn): v14 k-split chains, both halves per output j
        {
            const float* col = attn_W + (size_t)NH*NH + jl;
            double qA0,qA1,qB0,qB1;
            qhalf(col, 0,  s_h1[0], s_h1[1], qA0, qA1);
            qhalf(col, 64, s_h1[0], s_h1[1], qB0, qB1);
            s_qh[0][jl] = dAba[jl] + (qA0 + qB0);
            s_qh[1][jl] = dAba[jl] + (qA1 + qB1);
            const float* colh = attn_W + (size_t)NH*NH + jh;
            qhalf(colh, 0,  s_h1[0], s_h1[1], qA0, qA1);
            qhalf(colh, 64, s_h1[0], s_h1[1], qB0, qB1);
            s_qh[0][jh] = dAba[jh] + (qA0 + qB0);
            s_qh[1][jh] = dAba[jh] + (qA1 + qB1);
        }
        WB();
        // relu heads -> registers
        float lgL0, lgL1, lgH0 = 0.f, lgH1 = 0.f;
        lgL0 = relu_head(s_qh[0], dAa, t_va, s_c0[0][jl], s_c1[0][jl]);
        lgL1 = relu_head(s_qh[1], dAa, t_va, s_c0[1][jl], s_c1[1][jl]);
        if (hasHi) {
            lgH0 = relu_head(s_qh[0], dAa, t_va, s_c0[0][jh], s_c1[0][jh]);
            lgH1 = relu_head(s_qh[1], dAa, t_va, s_c0[1][jh], s_c1[1][jh]);
        }
        // softmax (per batch, wave-wide) -> s_a
        wave_softmax(lgL0, lgH0, hasHi, s_a[0]);
        wave_softmax(lgL1, lgH1, hasHi, s_a[1]);
        WB();
        // context + new ref_h
        s_x[0][NH+jl] = ctx_chain(s_a[0], s_c0[0], s_c1[0], t_wi0[jl], t_wi1[jl], t_bi[jl]);
        s_x[1][NH+jl] = ctx_chain(s_a[1], s_c0[1], s_c1[1], t_wi0[jl], t_wi1[jl], t_bi[jl]);
        s_x[0][NH+jh] = ctx_chain(s_a[0], s_c0[0], s_c1[0], t_wi0[jh], t_wi1[jh], t_bi[jh]);
        s_x[1][NH+jh] = ctx_chain(s_a[1], s_c0[1], s_c1[1], t_wi0[jh], t_wi1[jh], t_bi[jh]);
        {
            int sp0 = s_sol1[0][t], sp1 = s_sol1[1][t];
            s_x[0][jl] = fmaf(s_c0[0][sp0], t_wr0[jl], fmaf(s_c1[0][sp0], t_wr1[jl], t_br[jl]));
            s_x[0][jh] = fmaf(s_c0[0][sp0], t_wr0[jh], fmaf(s_c1[0][sp0], t_wr1[jh], t_br[jh]));
            s_x[1][jl] = fmaf(s_c0[1][sp1], t_wr0[jl], fmaf(s_c1[1][sp1], t_wr1[jl], t_br[jl]));
            s_x[1][jh] = fmaf(s_c0[1][sp1], t_wr0[jh], fmaf(s_c1[1][sp1], t_wr1[jh], t_br[jh]));
        }
        WB();
        // GRUd: x-side (K=256, new [ref|ctx]) + h-side (old h2) + gruc2
        {
            float da,db,dc,dd,de,df, Da,Db,Dc,Dd,De,Df;
            dot2x3f<64>(grud_Wih + (size_t)jl*256, grud_Wih + (size_t)(NH+jl)*256,
                        grud_Wih + (size_t)(2*NH+jl)*256, s_x[0], s_x[1], da,db,dc,dd,de,df);
            dot2x3f<64>(grud_Wih + (size_t)jh*256, grud_Wih + (size_t)(NH+jh)*256,
                        grud_Wih + (size_t)(2*NH+jh)*256, s_x[0], s_x[1], Da,Db,Dc,Dd,De,Df);
            float ha,hb,hc,hd,he,hf, Ha,Hb,Hc,Hd,He,Hf;
            dot2x3f<32>(grud_Whh + (size_t)jl*NH, grud_Whh + (size_t)(NH+jl)*NH,
                        grud_Whh + (size_t)(2*NH+jl)*NH, s_h2[0], s_h2[1], ha,hb,hc,hd,he,hf);
            dot2x3f<32>(grud_Whh + (size_t)jh*NH, grud_Whh + (size_t)(NH+jh)*NH,
                        grud_Whh + (size_t)(2*NH+jh)*NH, s_h2[0], s_h2[1], Ha,Hb,Hc,Hd,He,Hf);
            float m0l = grucr(t_dbih, t_dbhh, da,dc,de, ha,hc,he, s_h2[0][jl], jl);
            float m1l = grucr(t_dbih, t_dbhh, db,dd,df, hb,hd,hf, s_h2[1][jl], jl);
            float m0h = grucr(t_dbih, t_dbhh, Da,Dc,De, Ha,Hc,He, s_h2[0][jh], jh);
            float m1h = grucr(t_dbih, t_dbhh, Db,Dd,Df, Hb,Hd,Hf, s_h2[1][jh], jh);
            s_h2[0][jl] = m0l; s_h2[1][jl] = m1l; s_h2[0][jh] = m0h; s_h2[1][jh] = m1h;
        }
        WB();
    }

    // ---------- epilogue: mu, lv, Z (R9 verbatim chains) ----------
    for (int g = 0; g < 2; ++g) {
        const int b = bbase + g;
        {
            int s = jl;
            double mu = dotwd<32>(efc1_W + (size_t)s*NH, s_h2[g]) + (double)efc1_b[s];
            double lv = dotwd<32>(efc2_W + (size_t)s*NH, s_h2[g]) + (double)efc2_b[s];
            double z  = mu + (double)eps[(size_t)b*NS + s] * exp(0.5 * lv);
            out[OUT_MU + b*NS + s] = (float)mu;
            out[OUT_LV + b*NS + s] = (float)lv;
            out[OUT_Z  + b*NS + s] = (float)z;
            s_x[g][NH + s] = (float)z;
            s_msk[g][s] = 1.f;
        }
        if (hasHi) {
            int s = jh;
            double mu = dotwd<32>(efc1_W + (size_t)s*NH, s_h2[g]) + (double)efc1_b[s];
            double lv = dotwd<32>(efc2_W + (size_t)s*NH, s_h2[g]) + (double)efc2_b[s];
            double z  = mu + (double)eps[(size_t)b*NS + s] * exp(0.5 * lv);
            out[OUT_MU + b*NS + s] = (float)mu;
            out[OUT_LV + b*NS + s] = (float)lv;
            out[OUT_Z  + b*NS + s] = (float)z;
            s_x[g][NH + s] = (float)z;
            s_msk[g][s] = 1.f;
        }
    }
    s_h1[0][jl] = 0.f; s_h1[0][jh] = 0.f; s_h1[1][jl] = 0.f; s_h1[1][jh] = 0.f;
    WB();
    if (lane == 0) {
        for (int g = 0; g < 2; ++g) {
            int s0 = s_sol2[g][0];
            s_msk[g][s0] = 0.f;
            out[OUT_TI + (size_t)(bbase+g)*NS + 0] = (float)s0;
        }
    }
    WB();
    for (int g = 0; g < 2; ++g) {   // initial decoder ref
        int p0 = s_sol2[g][0];
        s_x[g][228 + jl] = fmaf(s_c0[g][p0], t_wr0[jl], fmaf(s_c1[g][p0], t_wr1[jl], t_br[jl]));
        s_x[g][228 + jh] = fmaf(s_c0[g][p0], t_wr0[jh], fmaf(s_c1[g][p0], t_wr1[jh], t_br[jh]));
    }
    WB();

    // ---------- decoder ----------
    for (int t = 1; t < NS; ++t) {
        // GRU1 on ref slot
        float xa,xb,xc,xd,xe,xf, ya,yb,yc,yd,ye,yf;
        dot2x3f<32>(gru_Wih + (size_t)jl*NH, gru_Wih + (size_t)(NH+jl)*NH,
                    gru_Wih + (size_t)(2*NH+jl)*NH, s_x[0]+228, s_x[1]+228, xa,xb,xc,xd,xe,xf);
        dot2x3f<32>(gru_Whh + (size_t)jl*NH, gru_Whh + (size_t)(NH+jl)*NH,
                    gru_Whh + (size_t)(2*NH+jl)*NH, s_h1[0], s_h1[1], ya,yb,yc,yd,ye,yf);
        float Xa,Xb,Xc,Xd,Xe,Xf, Ya,Yb,Yc,Yd,Ye,Yf;
        dot2x3f<32>(gru_Wih + (size_t)jh*NH, gru_Wih + (size_t)(NH+jh)*NH,
                    gru_Wih + (size_t)(2*NH+jh)*NH, s_x[0]+228, s_x[1]+228, Xa,Xb,Xc,Xd,Xe,Xf);
        dot2x3f<32>(gru_Whh + (size_t)jh*NH, gru_Whh + (size_t)(NH+jh)*NH,
                    gru_Whh + (size_t)(2*NH+jh)*NH, s_h1[0], s_h1[1], Ya,Yb,Yc,Yd,Ye,Yf);
        float n0l = grucr(t_gbih, t_gbhh, xa,xc,xe, ya,yc,ye, s_h1[0][jl], jl);
        float n1l = grucr(t_gbih, t_gbhh, xb,xd,xf, yb,yd,yf, s_h1[1][jl], jl);
        float n0h = grucr(t_gbih, t_gbhh, Xa,Xc,Xe, Ya,Yc,Ye, s_h1[0][jh], jh);
        float n1h = grucr(t_gbih, t_gbhh, Xb,Xd,Xf, Yb,Yd,Yf, s_h1[1][jh], jh);
        s_h1[0][jl] = n0l; s_h1[1][jl] = n1l; s_h1[0][jh] = n0h; s_h1[1][jh] = n1h;
        WB();
        // q (attn)
        {
            const float* col = attn_W + (size_t)NH*NH + jl;
            double qA0,qA1,qB0,qB1;
            qhalf(col, 0,  s_h1[0], s_h1[1], qA0, qA1);
            qhalf(col, 64, s_h1[0], s_h1[1], qB0, qB1);
            s_qh[0][jl] = dAba[jl] + (qA0 + qB0);
            s_qh[1][jl] = dAba[jl] + (qA1 + qB1);
            const float* colh = attn_W + (size_t)NH*NH + jh;
            qhalf(colh, 0,  s_h1[0], s_h1[1], qA0, qA1);
            qhalf(colh, 64, s_h1[0], s_h1[1], qB0, qB1);
            s_qh[0][jh] = dAba[jh] + (qA0 + qB0);
            s_qh[1][jh] = dAba[jh] + (qA1 + qB1);
        }
        WB();
        // relu heads + softmax1
        {
            float lgL0, lgL1, lgH0 = 0.f, lgH1 = 0.f;
            lgL0 = relu_head(s_qh[0], dAa, t_va, s_c0[0][jl], s_c1[0][jl]);
            lgL1 = relu_head(s_qh[1], dAa, t_va, s_c0[1][jl], s_c1[1][jl]);
            if (hasHi) {
                lgH0 = relu_head(s_qh[0], dAa, t_va, s_c0[0][jh], s_c1[0][jh]);
                lgH1 = relu_head(s_qh[1], dAa, t_va, s_c0[1][jh], s_c1[1][jh]);
            }
            wave_softmax(lgL0, lgH0, hasHi, s_a[0]);
            wave_softmax(lgL1, lgH1, hasHi, s_a[1]);
        }
        WB();
        // context -> s_x[g][0..127]
        s_x[0][jl] = ctx_chain(s_a[0], s_c0[0], s_c1[0], t_wi0[jl], t_wi1[jl], t_bi[jl]);
        s_x[1][jl] = ctx_chain(s_a[1], s_c0[1], s_c1[1], t_wi0[jl], t_wi1[jl], t_bi[jl]);
        s_x[0][jh] = ctx_chain(s_a[0], s_c0[0], s_c1[0], t_wi0[jh], t_wi1[jh], t_bi[jh]);
        s_x[1][jh] = ctx_chain(s_a[1], s_c0[1], s_c1[1], t_wi0[jh], t_wi1[jh], t_bi[jh]);
        WB();
        // pfc1: 4 rows per lane, shared W row -> 2 batches (v14 chain)
        #pragma unroll
        for (int p = 0; p < 4; ++p) {
            const int r = lane + (p << 6);
            float r0, r1;
            dot2f<89>(pfc1_W + (size_t)r * 356, s_x[0], s_x[1], r0, r1);
            float bb = t_p1b[r];
            s_fch[0][r] = r0 + bb; s_fch[1][r] = r1 + bb;
        }
        WB();
        // pfc2
        {
            float r0;
            dot1f<64>(pfc2_W + (size_t)jl * 256, s_fch[0], r0); s_fco[0][jl] = r0 + t_p2b[jl];
            dot1f<64>(pfc2_W + (size_t)jl * 256, s_fch[1], r0); s_fco[1][jl] = r0 + t_p2b[jl];
            dot1f<64>(pfc2_W + (size_t)jh * 256, s_fch[0], r0); s_fco[0][jh] = r0 + t_p2b[jh];
            dot1f<64>(pfc2_W + (size_t)jh * 256, s_fch[1], r0); s_fco[1][jh] = r0 + t_p2b[jh];
        }
        WB();
        // q2 (ptr on fc_out)
        {
            const float* col = ptr_W + (size_t)NH*NH + jl;
            double qA0,qA1,qB0,qB1;
            qhalf(col, 0,  s_fco[0], s_fco[1], qA0, qA1);
            qhalf(col, 64, s_fco[0], s_fco[1], qB0, qB1);
            s_qh[0][jl] = dAbp[jl] + (qA0 + qB0);
            s_qh[1][jl] = dAbp[jl] + (qA1 + qB1);
            const float* colh = ptr_W + (size_t)NH*NH + jh;
            qhalf(colh, 0,  s_fco[0], s_fco[1], qA0, qA1);
            qhalf(colh, 64, s_fco[0], s_fco[1], qB0, qB1);
            s_qh[0][jh] = dAbp[jh] + (qA0 + qB0);
            s_qh[1][jh] = dAbp[jh] + (qA1 + qB1);
        }
        WB();
        // tanh heads + masked softmax2 + argmax + outputs + next ref (per batch)
        {
            float lgL0, lgL1, lgH0 = 0.f, lgH1 = 0.f;
            lgL0 = tanh_head(s_qh[0], dAp, t_vp, s_c0[0][jl], s_c1[0][jl]);
            lgL1 = tanh_head(s_qh[1], dAp, t_vp, s_c0[1][jl], s_c1[1][jl]);
            if (hasHi) {
                lgH0 = tanh_head(s_qh[0], dAp, t_vp, s_c0[0][jh], s_c1[0][jh]);
                lgH1 = tanh_head(s_qh[1], dAp, t_vp, s_c0[1][jh], s_c1[1][jh]);
            }
            #pragma unroll
            for (int g = 0; g < 2; ++g) {
                float l1 = (g == 0) ? lgL0 : lgL1;
                float l2v = (g == 0) ? lgH0 : lgH1;
                bool u1 = s_msk[g][jl] > 0.f;
                float c1v = u1 ? l1 : NEGF;
                float l2 = 0.f; bool u2 = false; float c2v = NEGF;
                if (hasHi) { l2 = l2v; u2 = s_msk[g][jh] > 0.f; c2v = u2 ? l2 : NEGF; }
                float m = fmaxf(c1v, c2v);
                m = fmaxf(m, __shfl_xor(m, 32)); m = fmaxf(m, __shfl_xor(m, 16));
                m = fmaxf(m, __shfl_xor(m, 8));  m = fmaxf(m, __shfl_xor(m, 4));
                m = fmaxf(m, __shfl_xor(m, 2));  m = fmaxf(m, __shfl_xor(m, 1));
                float f1 = u1 ? (float)exp((double)l1 - (double)m) : 0.f;
                float f2 = (hasHi && u2) ? (float)exp((double)l2 - (double)m) : 0.f;
                float bv = f1; int bi = jl;
                if (hasHi && f2 > bv) { bv = f2; bi = jh; }
                double ps = (double)f1 + (double)f2;
                #pragma unroll
                for (int o = 32; o >= 1; o >>= 1) {
                    float  ov = __shfl_xor(bv, o);
                    int    oi = __shfl_xor(bi, o);
                    double op = __shfl_xor(ps, o);
                    ps += op;
                    if (ov > bv || (ov == bv && oi < bi)) { bv = ov; bi = oi; }
                }
                int pt = s_sol2[g][t];
                float a1s = __shfl(f1, pt & 63);
                float a2s = __shfl(f2, pt & 63);
                float a_pt = (pt < 64) ? a1s : a2s;
                if (lane == 0) {
                    int b2 = bbase + g;
                    double logp = log((double)a_pt / ps);
                    out[OUT_TI + (size_t)b2*NS + t]             = (float)bi;
                    out[OUT_LP + (size_t)b2*(NS-1) + (t-1)]     = (float)logp;
                    s_msk[g][pt] = 0.f;
                }
                float rc0 = s_c0[g][pt], rc1 = s_c1[g][pt];
                s_x[g][228 + jl] = fmaf(rc0, t_wr0[jl], fmaf(rc1, t_wr1[jl], t_br[jl]));
                s_x[g][228 + jh] = fmaf(rc0, t_wr0[jh], fmaf(rc1, t_wr1[jh], t_br[jh]));
            }
        }
        WB();
    }
}

extern "C" void kernel_launch(void* const* d_in, const int* in_sizes, int n_in,
                              void* d_out, int out_size, void* d_ws, size_t ws_size,
                              hipStream_t stream)
{
    (void)in_sizes; (void)n_in; (void)out_size; (void)d_ws; (void)ws_size;
    vae_v19<<<NBLK, NTHR, 0, stream>>>(
        (const float*)d_in[0], (const int*)d_in[1], (const int*)d_in[2], (const float*)d_in[3],
        (const float*)d_in[4], (const float*)d_in[5], (const float*)d_in[6], (const float*)d_in[7],
        (const float*)d_in[8], (const float*)d_in[9], (const float*)d_in[10], (const float*)d_in[11],
        (const float*)d_in[12], (const float*)d_in[13], (const float*)d_in[14], (const float*)d_in[15],
        (const float*)d_in[16], (const float*)d_in[17], (const float*)d_in[18], (const float*)d_in[19],
        (const float*)d_in[20], (const float*)d_in[21], (const float*)d_in[22], (const float*)d_in[23],
        (const float*)d_in[24], (const float*)d_in[25], (const float*)d_in[26], (const float*)d_in[27],
        (float*)d_out);
}

// Round 9
// 12090.970 us; speedup vs baseline: 1.6925x; 1.6925x over previous
//
#include <hip/hip_runtime.h>
#include <math.h>

static constexpr int NB  = 1024;
static constexpr int NS  = 100;
static constexpr int NH  = 128;
static constexpr int GPB = 2;           // batches per block
static constexpr int NTHR = 256;
static constexpr int NBLK = NB / GPB;   // 512 blocks, 2/CU
static constexpr int CH  = 4;           // decoder chunk (timesteps per D2 bulk)

static constexpr int OUT_MU = 0;
static constexpr int OUT_LV = NB * NS;
static constexpr int OUT_Z  = 2 * NB * NS;
static constexpr int OUT_TI = 3 * NB * NS;
static constexpr int OUT_LP = 4 * NB * NS;

#define NEGF (-3.4e38f)

// Fused 3-row x 2-batch f32 dot — per-accumulator fmaf chain k-ascending (v14 verbatim).
template<int C4>
__device__ __forceinline__ void dot2x3f(const float* __restrict__ wr0,
        const float* __restrict__ wr1, const float* __restrict__ wr2,
        const float* __restrict__ x0, const float* __restrict__ x1,
        float& r00, float& r01, float& r10, float& r11, float& r20, float& r21)
{
    const float4* W0 = reinterpret_cast<const float4*>(wr0);
    const float4* W1 = reinterpret_cast<const float4*>(wr1);
    const float4* W2 = reinterpret_cast<const float4*>(wr2);
    const float4* X0 = reinterpret_cast<const float4*>(x0);
    const float4* X1 = reinterpret_cast<const float4*>(x1);
    float a00 = 0.f, a01 = 0.f, a10 = 0.f, a11 = 0.f, a20 = 0.f, a21 = 0.f;
    #pragma unroll 4
    for (int c = 0; c < C4; ++c) {
        float4 u0 = W0[c], u1 = W1[c], u2 = W2[c];
        float4 v0 = X0[c], v1 = X1[c];
        a00 = fmaf(u0.x, v0.x, a00); a00 = fmaf(u0.y, v0.y, a00); a00 = fmaf(u0.z, v0.z, a00); a00 = fmaf(u0.w, v0.w, a00);
        a01 = fmaf(u0.x, v1.x, a01); a01 = fmaf(u0.y, v1.y, a01); a01 = fmaf(u0.z, v1.z, a01); a01 = fmaf(u0.w, v1.w, a01);
        a10 = fmaf(u1.x, v0.x, a10); a10 = fmaf(u1.y, v0.y, a10); a10 = fmaf(u1.z, v0.z, a10); a10 = fmaf(u1.w, v0.w, a10);
        a11 = fmaf(u1.x, v1.x, a11); a11 = fmaf(u1.y, v1.y, a11); a11 = fmaf(u1.z, v1.z, a11); a11 = fmaf(u1.w, v1.w, a11);
        a20 = fmaf(u2.x, v0.x, a20); a20 = fmaf(u2.y, v0.y, a20); a20 = fmaf(u2.z, v0.z, a20); a20 = fmaf(u2.w, v0.w, a20);
        a21 = fmaf(u2.x, v1.x, a21); a21 = fmaf(u2.y, v1.y, a21); a21 = fmaf(u2.z, v1.z, a21); a21 = fmaf(u2.w, v1.w, a21);
    }
    r00 = a00; r01 = a01; r10 = a10; r11 = a11; r20 = a20; r21 = a21;
}

// One weight row vs TWO LDS vectors — v14 verbatim per-accumulator chain.
template<int C4>
__device__ __forceinline__ void dot2f(const float* __restrict__ w,
        const float* __restrict__ x0, const float* __restrict__ x1, float& r0, float& r1)
{
    const float4* W = reinterpret_cast<const float4*>(w);
    const float4* X0 = reinterpret_cast<const float4*>(x0);
    const float4* X1 = reinterpret_cast<const float4*>(x1);
    float a0 = 0.f, a1 = 0.f;
    #pragma unroll 8
    for (int c = 0; c < C4; ++c) {
        float4 u = W[c];
        float4 v0 = X0[c], v1 = X1[c];
        a0 = fmaf(u.x, v0.x, a0); a0 = fmaf(u.y, v0.y, a0); a0 = fmaf(u.z, v0.z, a0); a0 = fmaf(u.w, v0.w, a0);
        a1 = fmaf(u.x, v1.x, a1); a1 = fmaf(u.y, v1.y, a1); a1 = fmaf(u.z, v1.z, a1); a1 = fmaf(u.w, v1.w, a1);
    }
    r0 = a0; r1 = a1;
}

// f64-accum dot (mu/lv epilogue) — R9 verbatim.
template<int C4>
__device__ __forceinline__ double dotwd(const float* __restrict__ w, const float* __restrict__ x)
{
    const float4* W = reinterpret_cast<const float4*>(w);
    double a = 0.0;
    #pragma unroll 8
    for (int c = 0; c < C4; ++c) {
        float4 u = W[c];
        const float* p = x + 4 * c;
        a = fma((double)u.x, (double)p[0], a);
        a = fma((double)u.y, (double)p[1], a);
        a = fma((double)u.z, (double)p[2], a);
        a = fma((double)u.w, (double)p[3], a);
    }
    return a;
}

// GRU nonlinearity (f64 internals, f32 storage) — R9 verbatim.
__device__ __forceinline__ void gruc(const float* __restrict__ bih, const float* __restrict__ bhh,
        const float* __restrict__ pa, const float* __restrict__ pb, float* __restrict__ h, int j)
{
    double r = 1.0 / (1.0 + exp(-(((double)pa[j]        + (double)bih[j])        + ((double)pb[j]        + (double)bhh[j]))));
    double z = 1.0 / (1.0 + exp(-(((double)pa[NH + j]   + (double)bih[NH + j])   + ((double)pb[NH + j]   + (double)bhh[NH + j]))));
    double n = tanh(((double)pa[2*NH + j] + (double)bih[2*NH + j]) + r * ((double)pb[2*NH + j] + (double)bhh[2*NH + j]));
    h[j] = (float)((1.0 - z) * n + z * (double)h[j]);
}

// q half-chain (v14-verbatim; HW-verified in v19): 4-acc f64 over 64 k, 2 vectors.
__device__ __forceinline__ void qhalf(const float* __restrict__ col, int k0,
        const float* __restrict__ hA, const float* __restrict__ hB, double& r0, double& r1)
{
    double a00=0.0,a01=0.0,a02=0.0,a03=0.0;
    double a10=0.0,a11=0.0,a12=0.0,a13=0.0;
    #pragma unroll 8
    for (int k = 0; k < 64; k += 4) {
        float w0 = col[(size_t)(k0+k+0) * NH];
        float w1 = col[(size_t)(k0+k+1) * NH];
        float w2 = col[(size_t)(k0+k+2) * NH];
        float w3 = col[(size_t)(k0+k+3) * NH];
        float4 h0 = *reinterpret_cast<const float4*>(&hA[k0+k]);
        float4 h1v = *reinterpret_cast<const float4*>(&hB[k0+k]);
        a00 = fma((double)w0, (double)h0.x, a00);
        a01 = fma((double)w1, (double)h0.y, a01);
        a02 = fma((double)w2, (double)h0.z, a02);
        a03 = fma((double)w3, (double)h0.w, a03);
        a10 = fma((double)w0, (double)h1v.x, a10);
        a11 = fma((double)w1, (double)h1v.y, a11);
        a12 = fma((double)w2, (double)h1v.z, a12);
        a13 = fma((double)w3, (double)h1v.w, a13);
    }
    r0 = (a00+a01)+(a02+a03); r1 = (a10+a11)+(a12+a13);
}

// relu head (v14-verbatim chain; HW-verified in v19). qh pre-combined.
__device__ __forceinline__ float relu_head(const double* __restrict__ qh,
        const double2* __restrict__ dA, const float* __restrict__ va, float c0v, float c1v)
{
    double c00 = (double)c0v, c10 = (double)c1v;
    double acc0=0.0,acc1=0.0,acc2=0.0,acc3=0.0;
    #pragma unroll 4
    for (int h = 0; h < NH; h += 4) {
        double2 A0=dA[h+0],A1=dA[h+1],A2=dA[h+2],A3=dA[h+3];
        double p0 = fma(c00,A0.x,fma(c10,A0.y,qh[h+0]));
        double p1 = fma(c00,A1.x,fma(c10,A1.y,qh[h+1]));
        double p2 = fma(c00,A2.x,fma(c10,A2.y,qh[h+2]));
        double p3 = fma(c00,A3.x,fma(c10,A3.y,qh[h+3]));
        acc0 = fma(fmax(p0,0.0),(double)va[h+0],acc0);
        acc1 = fma(fmax(p1,0.0),(double)va[h+1],acc1);
        acc2 = fma(fmax(p2,0.0),(double)va[h+2],acc2);
        acc3 = fma(fmax(p3,0.0),(double)va[h+3],acc3);
    }
    return (float)((acc0+acc1)+(acc2+acc3));
}

// tanh head (v14-verbatim chain; HW-verified in v19).
__device__ __forceinline__ float tanh_head(const double* __restrict__ qh,
        const double2* __restrict__ dA, const float* __restrict__ vp, float c0v, float c1v)
{
    double c00 = (double)c0v, c10 = (double)c1v;
    double acc0=0.0,acc1=0.0,acc2=0.0,acc3=0.0;
    #pragma unroll 4
    for (int h = 0; h < NH; h += 4) {
        double2 A0=dA[h+0],A1=dA[h+1],A2=dA[h+2],A3=dA[h+3];
        double p0 = fma(c00,A0.x,fma(c10,A0.y,qh[h+0]));
        double p1 = fma(c00,A1.x,fma(c10,A1.y,qh[h+1]));
        double p2 = fma(c00,A2.x,fma(c10,A2.y,qh[h+2]));
        double p3 = fma(c00,A3.x,fma(c10,A3.y,qh[h+3]));
        acc0 = fma((double)tanhf((float)p0),(double)vp[h+0],acc0);
        acc1 = fma((double)tanhf((float)p1),(double)vp[h+1],acc1);
        acc2 = fma((double)tanhf((float)p2),(double)vp[h+2],acc2);
        acc3 = fma((double)tanhf((float)p3),(double)vp[h+3],acc3);
    }
    return (float)((acc0+acc1)+(acc2+acc3));
}

// context chain (v14-verbatim; HW-verified in v19).
__device__ __forceinline__ float ctx_chain(const float* __restrict__ a,
        const float* __restrict__ c0, const float* __restrict__ c1,
        float w0, float w1, float bb)
{
    double a0=0.0,a1=0.0,a2=0.0,a3=0.0;
    #pragma unroll 5
    for (int s = 0; s < NS; s += 4) {
        float ih0 = fmaf(c0[s+0], w0, fmaf(c1[s+0], w1, bb));
        float ih1 = fmaf(c0[s+1], w0, fmaf(c1[s+1], w1, bb));
        float ih2 = fmaf(c0[s+2], w0, fmaf(c1[s+2], w1, bb));
        float ih3 = fmaf(c0[s+3], w0, fmaf(c1[s+3], w1, bb));
        a0 += (double)a[s+0] * (double)ih0;
        a1 += (double)a[s+1] * (double)ih1;
        a2 += (double)a[s+2] * (double)ih2;
        a3 += (double)a[s+3] * (double)ih3;
    }
    return (float)((a0+a1)+(a2+a3));
}

__global__ __launch_bounds__(NTHR) void vae_v20(
    const float* __restrict__ instance, const int* __restrict__ sol1,
    const int* __restrict__ sol2, const float* __restrict__ eps,
    const float* __restrict__ emb_i_W, const float* __restrict__ emb_i_b,
    const float* __restrict__ emb_r_W, const float* __restrict__ emb_r_b,
    const float* __restrict__ attn_W, const float* __restrict__ attn_v,
    const float* __restrict__ gru_Wih, const float* __restrict__ gru_Whh,
    const float* __restrict__ gru_bih, const float* __restrict__ gru_bhh,
    const float* __restrict__ grud_Wih, const float* __restrict__ grud_Whh,
    const float* __restrict__ grud_bih, const float* __restrict__ grud_bhh,
    const float* __restrict__ efc1_W, const float* __restrict__ efc1_b,
    const float* __restrict__ efc2_W, const float* __restrict__ efc2_b,
    const float* __restrict__ ptr_W, const float* __restrict__ ptr_v,
    const float* __restrict__ pfc1_W, const float* __restrict__ pfc1_b,
    const float* __restrict__ pfc2_W, const float* __restrict__ pfc2_b,
    float* __restrict__ out)
{
    __shared__ __align__(16) float  s_x[GPB][360];          // enc [ref|ctx]; Z kept at [128..227]
    __shared__ __align__(16) float  s_h1[GPB][NH], s_h2[GPB][NH];
    __shared__ float  s_pa[GPB][3 * NH], s_pb[GPB][3 * NH];
    __shared__ double2 dAa[NH], dAp[NH];
    __shared__ double dAba[NH], dAbp[NH];
    __shared__ float  s_lg[GPB][NS], s_a[GPB][NS];
    __shared__ float  s_c0[GPB][NS], s_c1[GPB][NS];
    __shared__ float  t_wi0[NH], t_wi1[NH], t_bi[NH];
    __shared__ float  t_wr0[NH], t_wr1[NH], t_br[NH];
    __shared__ float  t_va[NH], t_vp[NH];
    __shared__ float  t_gbih[3*NH], t_gbhh[3*NH], t_dbih[3*NH], t_dbhh[3*NH];
    __shared__ float  t_p1b[256], t_p2b[NH];
    __shared__ int    s_sol1[GPB][NS], s_sol2[GPB][NS];
    __shared__ double s_redd[GPB][2];
    // ---- decoder scratch ----
    __shared__ __align__(16) float  s_ref[GPB][NH];
    __shared__ __align__(16) float  h1buf[CH][GPB][NH];
    __shared__ float    rcb0[GPB][CH+1], rcb1[GPB][CH+1];
    __shared__ unsigned maskb[CH][GPB][4], m_run[GPB][4];
    __shared__ __align__(16) double d_qh[CH][GPB][NH];
    __shared__ __align__(16) float  d_pl[2*CH][NS];
    __shared__ __align__(16) float  d_x[2*CH][360];          // also hosts encoder qpA/qpB/qh (aliased)
    __shared__ __align__(16) float  d_fch[2*CH][256];
    __shared__ __align__(16) float  d_fco[CH][GPB][NH];

    // encoder q scratch aliased into d_x (decoder-inactive during encoder)
    double* e_dbuf = reinterpret_cast<double*>(&d_x[0][0]);
    #define E_QPA(g, jj) e_dbuf[(g)*128 + (jj)]
    #define E_QPB(g, jj) e_dbuf[256 + (g)*128 + (jj)]
    #define E_QH(g, jj)  e_dbuf[512 + (g)*128 + (jj)]

    const int tid = threadIdx.x;
    const int bbase = blockIdx.x * GPB;
    const int j = tid & (NH - 1);
    const int half = tid >> 7;
    const int g = half;
    const int lane = tid & 63;
    const int wid = (tid >> 6) & 1;
    const int k0 = half * 64;

    // ---------- init (v14 verbatim) ----------
    if (tid < NH) {
        t_wi0[tid] = emb_i_W[2*tid]; t_wi1[tid] = emb_i_W[2*tid+1]; t_bi[tid] = emb_i_b[tid];
        t_wr0[tid] = emb_r_W[2*tid]; t_wr1[tid] = emb_r_W[2*tid+1]; t_br[tid] = emb_r_b[tid];
        t_va[tid] = attn_v[tid]; t_vp[tid] = ptr_v[tid];
        t_p2b[tid] = pfc2_b[tid];
    }
    t_p1b[tid] = pfc1_b[tid];
    for (int i = tid; i < 3 * NH; i += NTHR) {
        t_gbih[i] = gru_bih[i]; t_gbhh[i] = gru_bhh[i];
        t_dbih[i] = grud_bih[i]; t_dbhh[i] = grud_bhh[i];
    }
    for (int i = tid; i < GPB * NS; i += NTHR) {
        int gg = i / NS, s = i - gg * NS;
        s_c0[gg][s] = instance[(size_t)((bbase + gg) * NS + s) * 2 + 0];
        s_c1[gg][s] = instance[(size_t)((bbase + gg) * NS + s) * 2 + 1];
        s_sol1[gg][s] = sol1[(bbase + gg) * NS + s];
        s_sol2[gg][s] = sol2[(bbase + gg) * NS + s];
    }
    s_h1[g][j] = 0.f;
    s_h2[g][j] = 0.f;
    __syncthreads();
    {   // collapse tables (R9 verbatim)
        const float* Wm = (half == 0) ? attn_W : ptr_W;
        double a0 = 0.0, a1 = 0.0, ab = 0.0;
        for (int k = 0; k < NH; ++k) {
            double wv2 = (double)Wm[(size_t)k * NH + j];
            a0 = fma((double)t_wi0[k], wv2, a0);
            a1 = fma((double)t_wi1[k], wv2, a1);
            ab = fma((double)t_bi[k],  wv2, ab);
        }
        if (half == 0) { dAa[j].x = a0; dAa[j].y = a1; dAba[j] = ab; }
        else           { dAp[j].x = a0; dAp[j].y = a1; dAbp[j] = ab; }
    }
    {   // initial encoder ref_h
        int sp = s_sol1[g][0];
        s_x[g][j] = fmaf(s_c0[g][sp], t_wr0[j], fmaf(s_c1[g][sp], t_wr1[j], t_br[j]));
    }
    __syncthreads();

    // ---------- encoder (v14 verbatim; qp/qh LDS aliased) ----------
    for (int t = 1; t < NS; ++t) {
        if (half == 0) {
            float a00,a01,a10,a11,a20,a21;
            dot2x3f<32>(gru_Wih + (size_t)j * NH, gru_Wih + (size_t)(NH + j) * NH,
                        gru_Wih + (size_t)(2*NH + j) * NH, s_x[0], s_x[1],
                        a00,a01,a10,a11,a20,a21);
            s_pa[0][j] = a00;        s_pa[1][j] = a01;
            s_pa[0][NH + j] = a10;   s_pa[1][NH + j] = a11;
            s_pa[0][2*NH + j] = a20; s_pa[1][2*NH + j] = a21;
        } else {
            float a00,a01,a10,a11,a20,a21;
            dot2x3f<32>(gru_Whh + (size_t)j * NH, gru_Whh + (size_t)(NH + j) * NH,
                        gru_Whh + (size_t)(2*NH + j) * NH, s_h1[0], s_h1[1],
                        a00,a01,a10,a11,a20,a21);
            s_pb[0][j] = a00;        s_pb[1][j] = a01;
            s_pb[0][NH + j] = a10;   s_pb[1][NH + j] = a11;
            s_pb[0][2*NH + j] = a20; s_pb[1][2*NH + j] = a21;
        }
        __syncthreads();
        gruc(t_gbih, t_gbhh, s_pa[g], s_pb[g], s_h1[g], j);
        __syncthreads();
        {   // q k-split (v14 verbatim chains)
            const float* col = attn_W + (size_t)NH * NH + j;
            double qA0, qA1;
            qhalf(col, k0, s_h1[0], s_h1[1], qA0, qA1);
            if (half == 0) { E_QPA(0, j) = qA0; E_QPA(1, j) = qA1; }
            else           { E_QPB(0, j) = qA0; E_QPB(1, j) = qA1; }
        }
        __syncthreads();
        E_QH(g, j) = dAba[j] + (E_QPA(g, j) + E_QPB(g, j));
        __syncthreads();
        if (j < NS) {   // relu head (v14 verbatim)
            double c00 = (double)s_c0[g][j], c10 = (double)s_c1[g][j];
            double acc0 = 0.0, acc1 = 0.0, acc2 = 0.0, acc3 = 0.0;
            #pragma unroll 4
            for (int h = 0; h < NH; h += 4) {
                double2 A0 = dAa[h+0], A1 = dAa[h+1], A2 = dAa[h+2], A3 = dAa[h+3];
                double p0 = fma(c00, A0.x, fma(c10, A0.y, E_QH(g, h+0)));
                double p1 = fma(c00, A1.x, fma(c10, A1.y, E_QH(g, h+1)));
                double p2 = fma(c00, A2.x, fma(c10, A2.y, E_QH(g, h+2)));
                double p3 = fma(c00, A3.x, fma(c10, A3.y, E_QH(g, h+3)));
                acc0 = fma(fmax(p0, 0.0), (double)t_va[h+0], acc0);
                acc1 = fma(fmax(p1, 0.0), (double)t_va[h+1], acc1);
                acc2 = fma(fmax(p2, 0.0), (double)t_va[h+2], acc2);
                acc3 = fma(fmax(p3, 0.0), (double)t_va[h+3], acc3);
            }
            s_lg[g][j] = (float)(((acc0 + acc1) + (acc2 + acc3)));
        }
        __syncthreads();
        {   // fused wave softmax (v14 verbatim)
            float a = s_lg[g][lane];
            float b = (lane + 64 < NS) ? s_lg[g][lane + 64] : NEGF;
            float m = fmaxf(a, b);
            m = fmaxf(m, __shfl_xor(m, 32)); m = fmaxf(m, __shfl_xor(m, 16));
            m = fmaxf(m, __shfl_xor(m, 8));  m = fmaxf(m, __shfl_xor(m, 4));
            m = fmaxf(m, __shfl_xor(m, 2));  m = fmaxf(m, __shfl_xor(m, 1));
            float fv = 0.f;
            if (j < NS) { fv = (float)exp((double)s_lg[g][j] - (double)m); s_a[g][j] = fv; }
            double ps = (double)fv;
            ps += __shfl_xor(ps, 32); ps += __shfl_xor(ps, 16);
            ps += __shfl_xor(ps, 8);  ps += __shfl_xor(ps, 4);
            ps += __shfl_xor(ps, 2);  ps += __shfl_xor(ps, 1);
            if (lane == 0) s_redd[g][wid] = ps;
        }
        __syncthreads();
        if (j < NS) {
            double se = s_redd[g][0] + s_redd[g][1];
            s_a[g][j] = (float)((double)s_a[g][j] / se);
        }
        __syncthreads();
        {   // context + new ref_h (v14 verbatim)
            s_x[g][NH + j] = ctx_chain(s_a[g], s_c0[g], s_c1[g], t_wi0[j], t_wi1[j], t_bi[j]);
            int sp = s_sol1[g][t];
            s_x[g][j] = fmaf(s_c0[g][sp], t_wr0[j], fmaf(s_c1[g][sp], t_wr1[j], t_br[j]));
        }
        __syncthreads();
        if (half == 0) {    // GRUd x-side (v14 verbatim)
            float a00,a01,a10,a11,a20,a21;
            dot2x3f<64>(grud_Wih + (size_t)j * 256, grud_Wih + (size_t)(NH + j) * 256,
                        grud_Wih + (size_t)(2*NH + j) * 256, s_x[0], s_x[1],
                        a00,a01,a10,a11,a20,a21);
            s_pa[0][j] = a00;        s_pa[1][j] = a01;
            s_pa[0][NH + j] = a10;   s_pa[1][NH + j] = a11;
            s_pa[0][2*NH + j] = a20; s_pa[1][2*NH + j] = a21;
        } else {            // GRUd h-side (v14 verbatim)
            float a00,a01,a10,a11,a20,a21;
            dot2x3f<32>(grud_Whh + (size_t)j * NH, grud_Whh + (size_t)(NH + j) * NH,
                        grud_Whh + (size_t)(2*NH + j) * NH, s_h2[0], s_h2[1],
                        a00,a01,a10,a11,a20,a21);
            s_pb[0][j] = a00;        s_pb[1][j] = a01;
            s_pb[0][NH + j] = a10;   s_pb[1][NH + j] = a11;
            s_pb[0][2*NH + j] = a20; s_pb[1][2*NH + j] = a21;
        }
        __syncthreads();
        gruc(t_dbih, t_dbhh, s_pa[g], s_pb[g], s_h2[g], j);
        __syncthreads();
    }

    // ---------- epilogue: mu, lv, Z (R9 verbatim) ----------
    for (int idx = tid; idx < GPB * NS; idx += NTHR) {
        int gg = idx / NS, s = idx - gg * NS, b = bbase + gg;
        double mu = dotwd<32>(efc1_W + (size_t)s * NH, s_h2[gg]) + (double)efc1_b[s];
        double lv = dotwd<32>(efc2_W + (size_t)s * NH, s_h2[gg]) + (double)efc2_b[s];
        double z  = mu + (double)eps[(size_t)b * NS + s] * exp(0.5 * lv);
        out[OUT_MU + b * NS + s] = (float)mu;
        out[OUT_LV + b * NS + s] = (float)lv;
        out[OUT_Z  + b * NS + s] = (float)z;
        s_x[gg][NH + s] = (float)z;   // Z slot [128..227], preserved through decoder
    }
    s_h1[g][j] = 0.f;
    __syncthreads();
    if (tid < GPB) {   // mask bitmap init (v15-verified) + TI[0]
        int b = bbase + tid;
        int s0 = s_sol2[tid][0];
        m_run[tid][0] = 0xFFFFFFFFu; m_run[tid][1] = 0xFFFFFFFFu;
        m_run[tid][2] = 0xFFFFFFFFu; m_run[tid][3] = 0xFu;
        m_run[tid][s0 >> 5] &= ~(1u << (s0 & 31));
        out[OUT_TI + b * NS + 0] = (float)s0;
    }
    __syncthreads();
    {   // initial decoder ref (same values v14 computed)
        int p0 = s_sol2[g][0];
        s_ref[g][j] = fmaf(s_c0[g][p0], t_wr0[j], fmaf(s_c1[g][p0], t_wr1[j], t_br[j]));
    }
    __syncthreads();

    // ---------- decoder: serial GRU chain + block-parallel bulk over CH steps ----------
    for (int c = 0; c < (NS - 1 + CH - 1) / CH; ++c) {
        const int t0 = 1 + c * CH;
        const int CHc = (t0 + CH <= NS) ? CH : (NS - t0);
        if (tid < GPB) {    // pre-phase: mask snapshots + ref coords (v15-verified)
            const int gg = tid;
            for (int qi = 0; qi <= CHc; ++qi) {
                int tt = t0 + qi;
                if (qi < CHc) {
                    maskb[qi][gg][0] = m_run[gg][0];
                    maskb[qi][gg][1] = m_run[gg][1];
                    maskb[qi][gg][2] = m_run[gg][2];
                    maskb[qi][gg][3] = m_run[gg][3];
                    int pt = s_sol2[gg][tt];
                    m_run[gg][pt >> 5] &= ~(1u << (pt & 31));
                }
                int sp = s_sol2[gg][tt - 1];
                rcb0[gg][qi] = s_c0[gg][sp];
                rcb1[gg][qi] = s_c1[gg][sp];
            }
        }
        __syncthreads();
        // ---- D1: serial GRU1 recurrence (v15-verified) ----
        for (int q = 0; q < CHc; ++q) {
            if (half == 0) {
                float a00,a01,a10,a11,a20,a21;
                dot2x3f<32>(gru_Wih + (size_t)j * NH, gru_Wih + (size_t)(NH + j) * NH,
                            gru_Wih + (size_t)(2*NH + j) * NH, s_ref[0], s_ref[1],
                            a00,a01,a10,a11,a20,a21);
                s_pa[0][j] = a00;        s_pa[1][j] = a01;
                s_pa[0][NH + j] = a10;   s_pa[1][NH + j] = a11;
                s_pa[0][2*NH + j] = a20; s_pa[1][2*NH + j] = a21;
            } else {
                float a00,a01,a10,a11,a20,a21;
                dot2x3f<32>(gru_Whh + (size_t)j * NH, gru_Whh + (size_t)(NH + j) * NH,
                            gru_Whh + (size_t)(2*NH + j) * NH, s_h1[0], s_h1[1],
                            a00,a01,a10,a11,a20,a21);
                s_pb[0][j] = a00;        s_pb[1][j] = a01;
                s_pb[0][NH + j] = a10;   s_pb[1][NH + j] = a11;
                s_pb[0][2*NH + j] = a20; s_pb[1][2*NH + j] = a21;
            }
            __syncthreads();
            gruc(t_gbih, t_gbhh, s_pa[g], s_pb[g], s_h1[g], j);
            h1buf[q][g][j] = s_h1[g][j];
            s_ref[g][j] = fmaf(rcb0[g][q+1], t_wr0[j], fmaf(rcb1[g][q+1], t_wr1[j], t_br[j]));
            __syncthreads();
        }
        // ---- P1: q (attn) — full-output per thread, v14 chains ----
        {
            const float* col = attn_W + (size_t)NH * NH + j;
            for (int tt = (tid >> 7); tt < CHc; tt += 2) {
                double qA0, qA1, qB0, qB1;
                qhalf(col, 0,  h1buf[tt][0], h1buf[tt][1], qA0, qA1);
                qhalf(col, 64, h1buf[tt][0], h1buf[tt][1], qB0, qB1);
                d_qh[tt][0][j] = dAba[j] + (qA0 + qB0);
                d_qh[tt][1][j] = dAba[j] + (qA1 + qB1);
            }
        }
        __syncthreads();
        // ---- P2: relu heads for all tasks ----
        for (int idx = tid; idx < 2 * CHc * NS; idx += NTHR) {
            int task = idx / NS, s = idx - task * NS;
            int tt = task >> 1, gg = task & 1;
            d_pl[task][s] = relu_head(d_qh[tt][gg], dAa, t_va, s_c0[gg][s], s_c1[gg][s]);
        }
        __syncthreads();
        // ---- P3: softmax1 per task, one wave each (v18-verified path) ----
        {
            int w = tid >> 6;
            for (int task = w; task < 2 * CHc; task += 4) {
                float v1 = d_pl[task][lane];
                bool hasHi = (lane + 64 < NS);
                float v2 = hasHi ? d_pl[task][lane + 64] : NEGF;
                float m = fmaxf(v1, v2);
                m = fmaxf(m, __shfl_xor(m, 32)); m = fmaxf(m, __shfl_xor(m, 16));
                m = fmaxf(m, __shfl_xor(m, 8));  m = fmaxf(m, __shfl_xor(m, 4));
                m = fmaxf(m, __shfl_xor(m, 2));  m = fmaxf(m, __shfl_xor(m, 1));
                float f1 = (float)exp((double)v1 - (double)m);
                float f2 = 0.f;
                if (hasHi) f2 = (float)exp((double)v2 - (double)m);
                double ps = (double)f1 + (double)f2;
                ps += __shfl_xor(ps, 32); ps += __shfl_xor(ps, 16);
                ps += __shfl_xor(ps, 8);  ps += __shfl_xor(ps, 4);
                ps += __shfl_xor(ps, 2);  ps += __shfl_xor(ps, 1);
                d_pl[task][lane] = (float)((double)f1 / ps);
                if (hasHi) d_pl[task][lane + 64] = (float)((double)f2 / ps);
            }
        }
        __syncthreads();
        // ---- P4: context + Z copy + ref into d_x ----
        for (int idx = tid; idx < 2 * CHc * NH; idx += NTHR) {
            int task = idx >> 7, jj = idx & 127;
            int tt = task >> 1, gg = task & 1;
            d_x[task][jj] = ctx_chain(d_pl[task], s_c0[gg], s_c1[gg], t_wi0[jj], t_wi1[jj], t_bi[jj]);
            float rc0 = rcb0[gg][tt], rc1 = rcb1[gg][tt];
            d_x[task][228 + jj] = fmaf(rc0, t_wr0[jj], fmaf(rc1, t_wr1[jj], t_br[jj]));
        }
        for (int idx = tid; idx < 2 * CHc * NS; idx += NTHR) {
            int task = idx / NS, s = idx - task * NS;
            int gg = task & 1;
            d_x[task][NH + s] = s_x[gg][NH + s];
        }
        __syncthreads();
        // ---- P5: pfc1 — row per thread, W reused across task pairs ----
        {
            const float* wrow = pfc1_W + (size_t)tid * 356;
            float bb = t_p1b[tid];
            for (int tt = 0; tt < CHc; ++tt) {
                float r0, r1;
                dot2f<89>(wrow, d_x[2*tt], d_x[2*tt+1], r0, r1);
                d_fch[2*tt][tid] = r0 + bb; d_fch[2*tt+1][tid] = r1 + bb;
            }
        }
        __syncthreads();
        // ---- P6: pfc2 ----
        {
            const float* wrow = pfc2_W + (size_t)j * 256;
            for (int tt = (tid >> 7); tt < CHc; tt += 2) {
                float r0, r1;
                dot2f<64>(wrow, d_fch[2*tt], d_fch[2*tt+1], r0, r1);
                d_fco[tt][0][j] = r0 + t_p2b[j];
                d_fco[tt][1][j] = r1 + t_p2b[j];
            }
        }
        __syncthreads();
        // ---- P7: q2 (ptr) ----
        {
            const float* col = ptr_W + (size_t)NH * NH + j;
            for (int tt = (tid >> 7); tt < CHc; tt += 2) {
                double qA0, qA1, qB0, qB1;
                qhalf(col, 0,  d_fco[tt][0], d_fco[tt][1], qA0, qA1);
                qhalf(col, 64, d_fco[tt][0], d_fco[tt][1], qB0, qB1);
                d_qh[tt][0][j] = dAbp[j] + (qA0 + qB0);
                d_qh[tt][1][j] = dAbp[j] + (qA1 + qB1);
            }
        }
        __syncthreads();
        // ---- P8: tanh heads ----
        for (int idx = tid; idx < 2 * CHc * NS; idx += NTHR) {
            int task = idx / NS, s = idx - task * NS;
            int tt = task >> 1, gg = task & 1;
            d_pl[task][s] = tanh_head(d_qh[tt][gg], dAp, t_vp, s_c0[gg][s], s_c1[gg][s]);
        }
        __syncthreads();
        // ---- P9: masked softmax2 + argmax + outputs, one wave per task (v15/v18-verified) ----
        {
            int w = tid >> 6;
            for (int task = w; task < 2 * CHc; task += 4) {
                int tt = task >> 1, gg = task & 1, tstep = t0 + tt;
                const unsigned* mwp = &maskb[tt][gg][0];
                bool u1 = (mwp[lane >> 5] >> (lane & 31)) & 1u;
                float l1 = d_pl[task][lane];
                float c1v = u1 ? l1 : NEGF;
                bool u2 = false; float l2 = 0.f, c2v = NEGF;
                if (lane + 64 < NS) {
                    u2 = (mwp[(lane + 64) >> 5] >> (lane & 31)) & 1u;
                    l2 = d_pl[task][lane + 64];
                    c2v = u2 ? l2 : NEGF;
                }
                float m = fmaxf(c1v, c2v);
                m = fmaxf(m, __shfl_xor(m, 32)); m = fmaxf(m, __shfl_xor(m, 16));
                m = fmaxf(m, __shfl_xor(m, 8));  m = fmaxf(m, __shfl_xor(m, 4));
                m = fmaxf(m, __shfl_xor(m, 2));  m = fmaxf(m, __shfl_xor(m, 1));
                float f1 = u1 ? (float)exp((double)l1 - (double)m) : 0.f;
                float f2 = (lane + 64 < NS && u2) ? (float)exp((double)l2 - (double)m) : 0.f;
                float bv = f1; int bi = lane;
                if (lane + 64 < NS && f2 > bv) { bv = f2; bi = lane + 64; }
                double ps = (double)f1 + (double)f2;
                #pragma unroll
                for (int o = 32; o >= 1; o >>= 1) {
                    float  ov = __shfl_xor(bv, o);
                    int    oi = __shfl_xor(bi, o);
                    double op = __shfl_xor(ps, o);
                    ps += op;
                    if (ov > bv || (ov == bv && oi < bi)) { bv = ov; bi = oi; }
                }
                int pt = s_sol2[gg][tstep];
                float a1s = __shfl(f1, pt & 63);
                float a2s = __shfl(f2, pt & 63);
                float a_pt = (pt < 64) ? a1s : a2s;
                if (lane == 0) {
                    int b2 = bbase + gg;
                    double logp = log((double)a_pt / ps);
                    out[OUT_TI + (size_t)b2 * NS + tstep]             = (float)bi;
                    out[OUT_LP + (size_t)b2 * (NS - 1) + (tstep - 1)] = (float)logp;
                }
            }
        }
        __syncthreads();
    }
    #undef E_QPA
    #undef E_QPB
    #undef E_QH
}

extern "C" void kernel_launch(void* const* d_in, const int* in_sizes, int n_in,
                              void* d_out, int out_size, void* d_ws, size_t ws_size,
                              hipStream_t stream)
{
    (void)in_sizes; (void)n_in; (void)out_size; (void)d_ws; (void)ws_size;
    vae_v20<<<NBLK, NTHR, 0, stream>>>(
        (const float*)d_in[0], (const int*)d_in[1], (const int*)d_in[2], (const float*)d_in[3],
        (const float*)d_in[4], (const float*)d_in[5], (const float*)d_in[6], (const float*)d_in[7],
        (const float*)d_in[8], (const float*)d_in[9], (const float*)d_in[10], (const float*)d_in[11],
        (const float*)d_in[12], (const float*)d_in[13], (const float*)d_in[14], (const float*)d_in[15],
        (const float*)d_in[16], (const float*)d_in[17], (const float*)d_in[18], (const float*)d_in[19],
        (const float*)d_in[20], (const float*)d_in[21], (const float*)d_in[22], (const float*)d_in[23],
        (const float*)d_in[24], (const float*)d_in[25], (const float*)d_in[26], (const float*)d_in[27],
        (float*)d_out);
}

// Round 10
// 11584.783 us; speedup vs baseline: 1.7664x; 1.0437x over previous
//
#include <hip/hip_runtime.h>
#include <math.h>

static constexpr int NB  = 1024;
static constexpr int NS  = 100;
static constexpr int NH  = 128;
static constexpr int GPB = 2;           // batches per block
static constexpr int NTHR = 256;
static constexpr int NBLK = NB / GPB;   // 512 blocks, 2/CU
static constexpr int CH  = 4;           // chunk (timesteps per bulk)

static constexpr int OUT_MU = 0;
static constexpr int OUT_LV = NB * NS;
static constexpr int OUT_Z  = 2 * NB * NS;
static constexpr int OUT_TI = 3 * NB * NS;
static constexpr int OUT_LP = 4 * NB * NS;

#define NEGF (-3.4e38f)

// Fused 3-row x 2-batch f32 dot — per-accumulator fmaf chain k-ascending (v14 verbatim).
template<int C4>
__device__ __forceinline__ void dot2x3f(const float* __restrict__ wr0,
        const float* __restrict__ wr1, const float* __restrict__ wr2,
        const float* __restrict__ x0, const float* __restrict__ x1,
        float& r00, float& r01, float& r10, float& r11, float& r20, float& r21)
{
    const float4* W0 = reinterpret_cast<const float4*>(wr0);
    const float4* W1 = reinterpret_cast<const float4*>(wr1);
    const float4* W2 = reinterpret_cast<const float4*>(wr2);
    const float4* X0 = reinterpret_cast<const float4*>(x0);
    const float4* X1 = reinterpret_cast<const float4*>(x1);
    float a00 = 0.f, a01 = 0.f, a10 = 0.f, a11 = 0.f, a20 = 0.f, a21 = 0.f;
    #pragma unroll 4
    for (int c = 0; c < C4; ++c) {
        float4 u0 = W0[c], u1 = W1[c], u2 = W2[c];
        float4 v0 = X0[c], v1 = X1[c];
        a00 = fmaf(u0.x, v0.x, a00); a00 = fmaf(u0.y, v0.y, a00); a00 = fmaf(u0.z, v0.z, a00); a00 = fmaf(u0.w, v0.w, a00);
        a01 = fmaf(u0.x, v1.x, a01); a01 = fmaf(u0.y, v1.y, a01); a01 = fmaf(u0.z, v1.z, a01); a01 = fmaf(u0.w, v1.w, a01);
        a10 = fmaf(u1.x, v0.x, a10); a10 = fmaf(u1.y, v0.y, a10); a10 = fmaf(u1.z, v0.z, a10); a10 = fmaf(u1.w, v0.w, a10);
        a11 = fmaf(u1.x, v1.x, a11); a11 = fmaf(u1.y, v1.y, a11); a11 = fmaf(u1.z, v1.z, a11); a11 = fmaf(u1.w, v1.w, a11);
        a20 = fmaf(u2.x, v0.x, a20); a20 = fmaf(u2.y, v0.y, a20); a20 = fmaf(u2.z, v0.z, a20); a20 = fmaf(u2.w, v0.w, a20);
        a21 = fmaf(u2.x, v1.x, a21); a21 = fmaf(u2.y, v1.y, a21); a21 = fmaf(u2.z, v1.z, a21); a21 = fmaf(u2.w, v1.w, a21);
    }
    r00 = a00; r01 = a01; r10 = a10; r11 = a11; r20 = a20; r21 = a21;
}

// One weight row vs TWO LDS vectors — v14 verbatim per-accumulator chain.
template<int C4>
__device__ __forceinline__ void dot2f(const float* __restrict__ w,
        const float* __restrict__ x0, const float* __restrict__ x1, float& r0, float& r1)
{
    const float4* W = reinterpret_cast<const float4*>(w);
    const float4* X0 = reinterpret_cast<const float4*>(x0);
    const float4* X1 = reinterpret_cast<const float4*>(x1);
    float a0 = 0.f, a1 = 0.f;
    #pragma unroll 8
    for (int c = 0; c < C4; ++c) {
        float4 u = W[c];
        float4 v0 = X0[c], v1 = X1[c];
        a0 = fmaf(u.x, v0.x, a0); a0 = fmaf(u.y, v0.y, a0); a0 = fmaf(u.z, v0.z, a0); a0 = fmaf(u.w, v0.w, a0);
        a1 = fmaf(u.x, v1.x, a1); a1 = fmaf(u.y, v1.y, a1); a1 = fmaf(u.z, v1.z, a1); a1 = fmaf(u.w, v1.w, a1);
    }
    r0 = a0; r1 = a1;
}

// f64-accum dot (mu/lv epilogue) — R9 verbatim.
template<int C4>
__device__ __forceinline__ double dotwd(const float* __restrict__ w, const float* __restrict__ x)
{
    const float4* W = reinterpret_cast<const float4*>(w);
    double a = 0.0;
    #pragma unroll 8
    for (int c = 0; c < C4; ++c) {
        float4 u = W[c];
        const float* p = x + 4 * c;
        a = fma((double)u.x, (double)p[0], a);
        a = fma((double)u.y, (double)p[1], a);
        a = fma((double)u.z, (double)p[2], a);
        a = fma((double)u.w, (double)p[3], a);
    }
    return a;
}

// GRU nonlinearity (f64 internals, f32 storage) — R9 verbatim.
__device__ __forceinline__ void gruc(const float* __restrict__ bih, const float* __restrict__ bhh,
        const float* __restrict__ pa, const float* __restrict__ pb, float* __restrict__ h, int j)
{
    double r = 1.0 / (1.0 + exp(-(((double)pa[j]        + (double)bih[j])        + ((double)pb[j]        + (double)bhh[j]))));
    double z = 1.0 / (1.0 + exp(-(((double)pa[NH + j]   + (double)bih[NH + j])   + ((double)pb[NH + j]   + (double)bhh[NH + j]))));
    double n = tanh(((double)pa[2*NH + j] + (double)bih[2*NH + j]) + r * ((double)pb[2*NH + j] + (double)bhh[2*NH + j]));
    h[j] = (float)((1.0 - z) * n + z * (double)h[j]);
}

// q half-chain (v14-verbatim; HW-verified v19/v20).
__device__ __forceinline__ void qhalf(const float* __restrict__ col, int k0,
        const float* __restrict__ hA, const float* __restrict__ hB, double& r0, double& r1)
{
    double a00=0.0,a01=0.0,a02=0.0,a03=0.0;
    double a10=0.0,a11=0.0,a12=0.0,a13=0.0;
    #pragma unroll 8
    for (int k = 0; k < 64; k += 4) {
        float w0 = col[(size_t)(k0+k+0) * NH];
        float w1 = col[(size_t)(k0+k+1) * NH];
        float w2 = col[(size_t)(k0+k+2) * NH];
        float w3 = col[(size_t)(k0+k+3) * NH];
        float4 h0 = *reinterpret_cast<const float4*>(&hA[k0+k]);
        float4 h1v = *reinterpret_cast<const float4*>(&hB[k0+k]);
        a00 = fma((double)w0, (double)h0.x, a00);
        a01 = fma((double)w1, (double)h0.y, a01);
        a02 = fma((double)w2, (double)h0.z, a02);
        a03 = fma((double)w3, (double)h0.w, a03);
        a10 = fma((double)w0, (double)h1v.x, a10);
        a11 = fma((double)w1, (double)h1v.y, a11);
        a12 = fma((double)w2, (double)h1v.z, a12);
        a13 = fma((double)w3, (double)h1v.w, a13);
    }
    r0 = (a00+a01)+(a02+a03); r1 = (a10+a11)+(a12+a13);
}

// relu head (v14-verbatim chain; HW-verified v19/v20). qh pre-combined.
__device__ __forceinline__ float relu_head(const double* __restrict__ qh,
        const double2* __restrict__ dA, const float* __restrict__ va, float c0v, float c1v)
{
    double c00 = (double)c0v, c10 = (double)c1v;
    double acc0=0.0,acc1=0.0,acc2=0.0,acc3=0.0;
    #pragma unroll 4
    for (int h = 0; h < NH; h += 4) {
        double2 A0=dA[h+0],A1=dA[h+1],A2=dA[h+2],A3=dA[h+3];
        double p0 = fma(c00,A0.x,fma(c10,A0.y,qh[h+0]));
        double p1 = fma(c00,A1.x,fma(c10,A1.y,qh[h+1]));
        double p2 = fma(c00,A2.x,fma(c10,A2.y,qh[h+2]));
        double p3 = fma(c00,A3.x,fma(c10,A3.y,qh[h+3]));
        acc0 = fma(fmax(p0,0.0),(double)va[h+0],acc0);
        acc1 = fma(fmax(p1,0.0),(double)va[h+1],acc1);
        acc2 = fma(fmax(p2,0.0),(double)va[h+2],acc2);
        acc3 = fma(fmax(p3,0.0),(double)va[h+3],acc3);
    }
    return (float)((acc0+acc1)+(acc2+acc3));
}

// tanh head (v14-verbatim chain; HW-verified v19/v20).
__device__ __forceinline__ float tanh_head(const double* __restrict__ qh,
        const double2* __restrict__ dA, const float* __restrict__ vp, float c0v, float c1v)
{
    double c00 = (double)c0v, c10 = (double)c1v;
    double acc0=0.0,acc1=0.0,acc2=0.0,acc3=0.0;
    #pragma unroll 4
    for (int h = 0; h < NH; h += 4) {
        double2 A0=dA[h+0],A1=dA[h+1],A2=dA[h+2],A3=dA[h+3];
        double p0 = fma(c00,A0.x,fma(c10,A0.y,qh[h+0]));
        double p1 = fma(c00,A1.x,fma(c10,A1.y,qh[h+1]));
        double p2 = fma(c00,A2.x,fma(c10,A2.y,qh[h+2]));
        double p3 = fma(c00,A3.x,fma(c10,A3.y,qh[h+3]));
        acc0 = fma((double)tanhf((float)p0),(double)vp[h+0],acc0);
        acc1 = fma((double)tanhf((float)p1),(double)vp[h+1],acc1);
        acc2 = fma((double)tanhf((float)p2),(double)vp[h+2],acc2);
        acc3 = fma((double)tanhf((float)p3),(double)vp[h+3],acc3);
    }
    return (float)((acc0+acc1)+(acc2+acc3));
}

// context chain (v14-verbatim; HW-verified v19/v20).
__device__ __forceinline__ float ctx_chain(const float* __restrict__ a,
        const float* __restrict__ c0, const float* __restrict__ c1,
        float w0, float w1, float bb)
{
    double a0=0.0,a1=0.0,a2=0.0,a3=0.0;
    #pragma unroll 5
    for (int s = 0; s < NS; s += 4) {
        float ih0 = fmaf(c0[s+0], w0, fmaf(c1[s+0], w1, bb));
        float ih1 = fmaf(c0[s+1], w0, fmaf(c1[s+1], w1, bb));
        float ih2 = fmaf(c0[s+2], w0, fmaf(c1[s+2], w1, bb));
        float ih3 = fmaf(c0[s+3], w0, fmaf(c1[s+3], w1, bb));
        a0 += (double)a[s+0] * (double)ih0;
        a1 += (double)a[s+1] * (double)ih1;
        a2 += (double)a[s+2] * (double)ih2;
        a3 += (double)a[s+3] * (double)ih3;
    }
    return (float)((a0+a1)+(a2+a3));
}

__global__ __launch_bounds__(NTHR) void vae_v21(
    const float* __restrict__ instance, const int* __restrict__ sol1,
    const int* __restrict__ sol2, const float* __restrict__ eps,
    const float* __restrict__ emb_i_W, const float* __restrict__ emb_i_b,
    const float* __restrict__ emb_r_W, const float* __restrict__ emb_r_b,
    const float* __restrict__ attn_W, const float* __restrict__ attn_v,
    const float* __restrict__ gru_Wih, const float* __restrict__ gru_Whh,
    const float* __restrict__ gru_bih, const float* __restrict__ gru_bhh,
    const float* __restrict__ grud_Wih, const float* __restrict__ grud_Whh,
    const float* __restrict__ grud_bih, const float* __restrict__ grud_bhh,
    const float* __restrict__ efc1_W, const float* __restrict__ efc1_b,
    const float* __restrict__ efc2_W, const float* __restrict__ efc2_b,
    const float* __restrict__ ptr_W, const float* __restrict__ ptr_v,
    const float* __restrict__ pfc1_W, const float* __restrict__ pfc1_b,
    const float* __restrict__ pfc2_W, const float* __restrict__ pfc2_b,
    float* __restrict__ out)
{
    __shared__ __align__(16) float  s_x[GPB][360];          // Z kept at [128..227] for decoder
    __shared__ __align__(16) float  s_h1[GPB][NH], s_h2[GPB][NH];
    __shared__ float  s_pa[GPB][3 * NH], s_pb[GPB][3 * NH];
    __shared__ double2 dAa[NH], dAp[NH];
    __shared__ double dAba[NH], dAbp[NH];
    __shared__ float  s_c0[GPB][NS], s_c1[GPB][NS];
    __shared__ float  t_wi0[NH], t_wi1[NH], t_bi[NH];
    __shared__ float  t_wr0[NH], t_wr1[NH], t_br[NH];
    __shared__ float  t_va[NH], t_vp[NH];
    __shared__ float  t_gbih[3*NH], t_gbhh[3*NH], t_dbih[3*NH], t_dbhh[3*NH];
    __shared__ float  t_p1b[256], t_p2b[NH];
    __shared__ int    s_sol1[GPB][NS], s_sol2[GPB][NS];
    // ---- chunk scratch (shared by encoder and decoder bulk) ----
    __shared__ __align__(16) float  s_ref[GPB][NH];
    __shared__ __align__(16) float  h1buf[CH][GPB][NH];
    __shared__ float    rcb0[GPB][CH+1], rcb1[GPB][CH+1];
    __shared__ unsigned maskb[CH][GPB][4], m_run[GPB][4];
    __shared__ __align__(16) double d_qh[CH][GPB][NH];
    __shared__ __align__(16) float  d_pl[2*CH][NS];
    __shared__ __align__(16) float  d_x[2*CH][360];
    __shared__ __align__(16) float  d_fch[2*CH][256];
    __shared__ __align__(16) float  d_fco[CH][GPB][NH];

    const int tid = threadIdx.x;
    const int bbase = blockIdx.x * GPB;
    const int j = tid & (NH - 1);
    const int half = tid >> 7;
    const int g = half;
    const int lane = tid & 63;

    // ---------- init (v14 verbatim) ----------
    if (tid < NH) {
        t_wi0[tid] = emb_i_W[2*tid]; t_wi1[tid] = emb_i_W[2*tid+1]; t_bi[tid] = emb_i_b[tid];
        t_wr0[tid] = emb_r_W[2*tid]; t_wr1[tid] = emb_r_W[2*tid+1]; t_br[tid] = emb_r_b[tid];
        t_va[tid] = attn_v[tid]; t_vp[tid] = ptr_v[tid];
        t_p2b[tid] = pfc2_b[tid];
    }
    t_p1b[tid] = pfc1_b[tid];
    for (int i = tid; i < 3 * NH; i += NTHR) {
        t_gbih[i] = gru_bih[i]; t_gbhh[i] = gru_bhh[i];
        t_dbih[i] = grud_bih[i]; t_dbhh[i] = grud_bhh[i];
    }
    for (int i = tid; i < GPB * NS; i += NTHR) {
        int gg = i / NS, s = i - gg * NS;
        s_c0[gg][s] = instance[(size_t)((bbase + gg) * NS + s) * 2 + 0];
        s_c1[gg][s] = instance[(size_t)((bbase + gg) * NS + s) * 2 + 1];
        s_sol1[gg][s] = sol1[(bbase + gg) * NS + s];
        s_sol2[gg][s] = sol2[(bbase + gg) * NS + s];
    }
    s_h1[g][j] = 0.f;
    s_h2[g][j] = 0.f;
    __syncthreads();
    {   // collapse tables (R9 verbatim)
        const float* Wm = (half == 0) ? attn_W : ptr_W;
        double a0 = 0.0, a1 = 0.0, ab = 0.0;
        for (int k = 0; k < NH; ++k) {
            double wv2 = (double)Wm[(size_t)k * NH + j];
            a0 = fma((double)t_wi0[k], wv2, a0);
            a1 = fma((double)t_wi1[k], wv2, a1);
            ab = fma((double)t_bi[k],  wv2, ab);
        }
        if (half == 0) { dAa[j].x = a0; dAa[j].y = a1; dAba[j] = ab; }
        else           { dAp[j].x = a0; dAp[j].y = a1; dAbp[j] = ab; }
    }
    {   // initial encoder ref (sol1[0]) — same values v14 put in s_x[g][j]
        int sp = s_sol1[g][0];
        s_ref[g][j] = fmaf(s_c0[g][sp], t_wr0[j], fmaf(s_c1[g][sp], t_wr1[j], t_br[j]));
    }
    __syncthreads();

    // ---------- encoder: chunked h1-serial + bulk heads + h2-serial ----------
    for (int c = 0; c < (NS - 1 + CH - 1) / CH; ++c) {
        const int t0 = 1 + c * CH;
        const int CHc = (t0 + CH <= NS) ? CH : (NS - t0);
        if (tid < GPB) {    // pre: enc ref coords from sol1 (data-independent)
            const int gg = tid;
            for (int qi = 0; qi < CHc; ++qi) {
                int sp = s_sol1[gg][t0 + qi];
                rcb0[gg][qi] = s_c0[gg][sp];
                rcb1[gg][qi] = s_c1[gg][sp];
            }
        }
        __syncthreads();
        // ---- E1: h1 serial (v14 PH1/PH2 chains; v15-D1 pattern) ----
        for (int q = 0; q < CHc; ++q) {
            if (half == 0) {
                float a00,a01,a10,a11,a20,a21;
                dot2x3f<32>(gru_Wih + (size_t)j * NH, gru_Wih + (size_t)(NH + j) * NH,
                            gru_Wih + (size_t)(2*NH + j) * NH, s_ref[0], s_ref[1],
                            a00,a01,a10,a11,a20,a21);
                s_pa[0][j] = a00;        s_pa[1][j] = a01;
                s_pa[0][NH + j] = a10;   s_pa[1][NH + j] = a11;
                s_pa[0][2*NH + j] = a20; s_pa[1][2*NH + j] = a21;
            } else {
                float a00,a01,a10,a11,a20,a21;
                dot2x3f<32>(gru_Whh + (size_t)j * NH, gru_Whh + (size_t)(NH + j) * NH,
                            gru_Whh + (size_t)(2*NH + j) * NH, s_h1[0], s_h1[1],
                            a00,a01,a10,a11,a20,a21);
                s_pb[0][j] = a00;        s_pb[1][j] = a01;
                s_pb[0][NH + j] = a10;   s_pb[1][NH + j] = a11;
                s_pb[0][2*NH + j] = a20; s_pb[1][2*NH + j] = a21;
            }
            __syncthreads();
            gruc(t_gbih, t_gbhh, s_pa[g], s_pb[g], s_h1[g], j);
            h1buf[q][g][j] = s_h1[g][j];
            // next step's x-input ref = emb_r(sol1[t0+q])
            s_ref[g][j] = fmaf(rcb0[g][q], t_wr0[j], fmaf(rcb1[g][q], t_wr1[j], t_br[j]));
            __syncthreads();
        }
        // ---- P1: q (attn) bulk — v20-P1 verbatim on h1buf ----
        {
            const float* col = attn_W + (size_t)NH * NH + j;
            for (int tt = (tid >> 7); tt < CHc; tt += 2) {
                double qA0, qA1, qB0, qB1;
                qhalf(col, 0,  h1buf[tt][0], h1buf[tt][1], qA0, qA1);
                qhalf(col, 64, h1buf[tt][0], h1buf[tt][1], qB0, qB1);
                d_qh[tt][0][j] = dAba[j] + (qA0 + qB0);
                d_qh[tt][1][j] = dAba[j] + (qA1 + qB1);
            }
        }
        __syncthreads();
        // ---- P2: relu heads bulk — v20-P2 verbatim ----
        for (int idx = tid; idx < 2 * CHc * NS; idx += NTHR) {
            int task = idx / NS, s = idx - task * NS;
            int tt = task >> 1, gg = task & 1;
            d_pl[task][s] = relu_head(d_qh[tt][gg], dAa, t_va, s_c0[gg][s], s_c1[gg][s]);
        }
        __syncthreads();
        // ---- P3: softmax1 bulk, one wave per task — v20-P3 verbatim ----
        {
            int w = tid >> 6;
            for (int task = w; task < 2 * CHc; task += 4) {
                float v1 = d_pl[task][lane];
                bool hasHi = (lane + 64 < NS);
                float v2 = hasHi ? d_pl[task][lane + 64] : NEGF;
                float m = fmaxf(v1, v2);
                m = fmaxf(m, __shfl_xor(m, 32)); m = fmaxf(m, __shfl_xor(m, 16));
                m = fmaxf(m, __shfl_xor(m, 8));  m = fmaxf(m, __shfl_xor(m, 4));
                m = fmaxf(m, __shfl_xor(m, 2));  m = fmaxf(m, __shfl_xor(m, 1));
                float f1 = (float)exp((double)v1 - (double)m);
                float f2 = 0.f;
                if (hasHi) f2 = (float)exp((double)v2 - (double)m);
                double ps = (double)f1 + (double)f2;
                ps += __shfl_xor(ps, 32); ps += __shfl_xor(ps, 16);
                ps += __shfl_xor(ps, 8);  ps += __shfl_xor(ps, 4);
                ps += __shfl_xor(ps, 2);  ps += __shfl_xor(ps, 1);
                d_pl[task][lane] = (float)((double)f1 / ps);
                if (hasHi) d_pl[task][lane + 64] = (float)((double)f2 / ps);
            }
        }
        __syncthreads();
        // ---- P4: ctx + new-ref into d_x ([ref_new | ctx] layout = v14 s_x) ----
        for (int idx = tid; idx < 2 * CHc * NH; idx += NTHR) {
            int task = idx >> 7, jj = idx & 127;
            int tt = task >> 1, gg = task & 1;
            d_x[task][NH + jj] = ctx_chain(d_pl[task], s_c0[gg], s_c1[gg], t_wi0[jj], t_wi1[jj], t_bi[jj]);
            d_x[task][jj] = fmaf(rcb0[gg][tt], t_wr0[jj], fmaf(rcb1[gg][tt], t_wr1[jj], t_br[jj]));
        }
        __syncthreads();
        // ---- E2: h2 serial — v14's GRUd dots+gruc2 phases, x from d_x ----
        for (int q = 0; q < CHc; ++q) {
            if (half == 0) {    // x-side (v14 verbatim chains)
                float a00,a01,a10,a11,a20,a21;
                dot2x3f<64>(grud_Wih + (size_t)j * 256, grud_Wih + (size_t)(NH + j) * 256,
                            grud_Wih + (size_t)(2*NH + j) * 256, d_x[2*q], d_x[2*q+1],
                            a00,a01,a10,a11,a20,a21);
                s_pa[0][j] = a00;        s_pa[1][j] = a01;
                s_pa[0][NH + j] = a10;   s_pa[1][NH + j] = a11;
                s_pa[0][2*NH + j] = a20; s_pa[1][2*NH + j] = a21;
            } else {            // h-side (v14 verbatim chains)
                float a00,a01,a10,a11,a20,a21;
                dot2x3f<32>(grud_Whh + (size_t)j * NH, grud_Whh + (size_t)(NH + j) * NH,
                            grud_Whh + (size_t)(2*NH + j) * NH, s_h2[0], s_h2[1],
                            a00,a01,a10,a11,a20,a21);
                s_pb[0][j] = a00;        s_pb[1][j] = a01;
                s_pb[0][NH + j] = a10;   s_pb[1][NH + j] = a11;
                s_pb[0][2*NH + j] = a20; s_pb[1][2*NH + j] = a21;
            }
            __syncthreads();
            gruc(t_dbih, t_dbhh, s_pa[g], s_pb[g], s_h2[g], j);
            __syncthreads();
        }
    }

    // ---------- epilogue: mu, lv, Z (R9 verbatim) ----------
    for (int idx = tid; idx < GPB * NS; idx += NTHR) {
        int gg = idx / NS, s = idx - gg * NS, b = bbase + gg;
        double mu = dotwd<32>(efc1_W + (size_t)s * NH, s_h2[gg]) + (double)efc1_b[s];
        double lv = dotwd<32>(efc2_W + (size_t)s * NH, s_h2[gg]) + (double)efc2_b[s];
        double z  = mu + (double)eps[(size_t)b * NS + s] * exp(0.5 * lv);
        out[OUT_MU + b * NS + s] = (float)mu;
        out[OUT_LV + b * NS + s] = (float)lv;
        out[OUT_Z  + b * NS + s] = (float)z;
        s_x[gg][NH + s] = (float)z;   // Z slot [128..227], preserved through decoder
    }
    s_h1[g][j] = 0.f;
    __syncthreads();
    if (tid < GPB) {   // mask bitmap init (v15-verified) + TI[0]
        int b = bbase + tid;
        int s0 = s_sol2[tid][0];
        m_run[tid][0] = 0xFFFFFFFFu; m_run[tid][1] = 0xFFFFFFFFu;
        m_run[tid][2] = 0xFFFFFFFFu; m_run[tid][3] = 0xFu;
        m_run[tid][s0 >> 5] &= ~(1u << (s0 & 31));
        out[OUT_TI + b * NS + 0] = (float)s0;
    }
    __syncthreads();
    {   // initial decoder ref
        int p0 = s_sol2[g][0];
        s_ref[g][j] = fmaf(s_c0[g][p0], t_wr0[j], fmaf(s_c1[g][p0], t_wr1[j], t_br[j]));
    }
    __syncthreads();

    // ---------- decoder (v20 verbatim) ----------
    for (int c = 0; c < (NS - 1 + CH - 1) / CH; ++c) {
        const int t0 = 1 + c * CH;
        const int CHc = (t0 + CH <= NS) ? CH : (NS - t0);
        if (tid < GPB) {    // pre-phase: mask snapshots + ref coords (v15-verified)
            const int gg = tid;
            for (int qi = 0; qi <= CHc; ++qi) {
                int tt = t0 + qi;
                if (qi < CHc) {
                    maskb[qi][gg][0] = m_run[gg][0];
                    maskb[qi][gg][1] = m_run[gg][1];
                    maskb[qi][gg][2] = m_run[gg][2];
                    maskb[qi][gg][3] = m_run[gg][3];
                    int pt = s_sol2[gg][tt];
                    m_run[gg][pt >> 5] &= ~(1u << (pt & 31));
                }
                int sp = s_sol2[gg][tt - 1];
                rcb0[gg][qi] = s_c0[gg][sp];
                rcb1[gg][qi] = s_c1[gg][sp];
            }
        }
        __syncthreads();
        // ---- D1: serial GRU1 recurrence (v15-verified) ----
        for (int q = 0; q < CHc; ++q) {
            if (half == 0) {
                float a00,a01,a10,a11,a20,a21;
                dot2x3f<32>(gru_Wih + (size_t)j * NH, gru_Wih + (size_t)(NH + j) * NH,
                            gru_Wih + (size_t)(2*NH + j) * NH, s_ref[0], s_ref[1],
                            a00,a01,a10,a11,a20,a21);
                s_pa[0][j] = a00;        s_pa[1][j] = a01;
                s_pa[0][NH + j] = a10;   s_pa[1][NH + j] = a11;
                s_pa[0][2*NH + j] = a20; s_pa[1][2*NH + j] = a21;
            } else {
                float a00,a01,a10,a11,a20,a21;
                dot2x3f<32>(gru_Whh + (size_t)j * NH, gru_Whh + (size_t)(NH + j) * NH,
                            gru_Whh + (size_t)(2*NH + j) * NH, s_h1[0], s_h1[1],
                            a00,a01,a10,a11,a20,a21);
                s_pb[0][j] = a00;        s_pb[1][j] = a01;
                s_pb[0][NH + j] = a10;   s_pb[1][NH + j] = a11;
                s_pb[0][2*NH + j] = a20; s_pb[1][2*NH + j] = a21;
            }
            __syncthreads();
            gruc(t_gbih, t_gbhh, s_pa[g], s_pb[g], s_h1[g], j);
            h1buf[q][g][j] = s_h1[g][j];
            s_ref[g][j] = fmaf(rcb0[g][q+1], t_wr0[j], fmaf(rcb1[g][q+1], t_wr1[j], t_br[j]));
            __syncthreads();
        }
        // ---- P1: q (attn) — v20 verbatim ----
        {
            const float* col = attn_W + (size_t)NH * NH + j;
            for (int tt = (tid >> 7); tt < CHc; tt += 2) {
                double qA0, qA1, qB0, qB1;
                qhalf(col, 0,  h1buf[tt][0], h1buf[tt][1], qA0, qA1);
                qhalf(col, 64, h1buf[tt][0], h1buf[tt][1], qB0, qB1);
                d_qh[tt][0][j] = dAba[j] + (qA0 + qB0);
                d_qh[tt][1][j] = dAba[j] + (qA1 + qB1);
            }
        }
        __syncthreads();
        // ---- P2: relu heads — v20 verbatim ----
        for (int idx = tid; idx < 2 * CHc * NS; idx += NTHR) {
            int task = idx / NS, s = idx - task * NS;
            int tt = task >> 1, gg = task & 1;
            d_pl[task][s] = relu_head(d_qh[tt][gg], dAa, t_va, s_c0[gg][s], s_c1[gg][s]);
        }
        __syncthreads();
        // ---- P3: softmax1 — v20 verbatim ----
        {
            int w = tid >> 6;
            for (int task = w; task < 2 * CHc; task += 4) {
                float v1 = d_pl[task][lane];
                bool hasHi = (lane + 64 < NS);
                float v2 = hasHi ? d_pl[task][lane + 64] : NEGF;
                float m = fmaxf(v1, v2);
                m = fmaxf(m, __shfl_xor(m, 32)); m = fmaxf(m, __shfl_xor(m, 16));
                m = fmaxf(m, __shfl_xor(m, 8));  m = fmaxf(m, __shfl_xor(m, 4));
                m = fmaxf(m, __shfl_xor(m, 2));  m = fmaxf(m, __shfl_xor(m, 1));
                float f1 = (float)exp((double)v1 - (double)m);
                float f2 = 0.f;
                if (hasHi) f2 = (float)exp((double)v2 - (double)m);
                double ps = (double)f1 + (double)f2;
                ps += __shfl_xor(ps, 32); ps += __shfl_xor(ps, 16);
                ps += __shfl_xor(ps, 8);  ps += __shfl_xor(ps, 4);
                ps += __shfl_xor(ps, 2);  ps += __shfl_xor(ps, 1);
                d_pl[task][lane] = (float)((double)f1 / ps);
                if (hasHi) d_pl[task][lane + 64] = (float)((double)f2 / ps);
            }
        }
        __syncthreads();
        // ---- P4: context + Z copy + ref into d_x — v20 verbatim ----
        for (int idx = tid; idx < 2 * CHc * NH; idx += NTHR) {
            int task = idx >> 7, jj = idx & 127;
            int tt = task >> 1, gg = task & 1;
            d_x[task][jj] = ctx_chain(d_pl[task], s_c0[gg], s_c1[gg], t_wi0[jj], t_wi1[jj], t_bi[jj]);
            float rc0 = rcb0[gg][tt], rc1 = rcb1[gg][tt];
            d_x[task][228 + jj] = fmaf(rc0, t_wr0[jj], fmaf(rc1, t_wr1[jj], t_br[jj]));
        }
        for (int idx = tid; idx < 2 * CHc * NS; idx += NTHR) {
            int task = idx / NS, s = idx - task * NS;
            int gg = task & 1;
            d_x[task][NH + s] = s_x[gg][NH + s];
        }
        __syncthreads();
        // ---- P5: pfc1 — v20 verbatim ----
        {
            const float* wrow = pfc1_W + (size_t)tid * 356;
            float bb = t_p1b[tid];
            for (int tt = 0; tt < CHc; ++tt) {
                float r0, r1;
                dot2f<89>(wrow, d_x[2*tt], d_x[2*tt+1], r0, r1);
                d_fch[2*tt][tid] = r0 + bb; d_fch[2*tt+1][tid] = r1 + bb;
            }
        }
        __syncthreads();
        // ---- P6: pfc2 — v20 verbatim ----
        {
            const float* wrow = pfc2_W + (size_t)j * 256;
            for (int tt = (tid >> 7); tt < CHc; tt += 2) {
                float r0, r1;
                dot2f<64>(wrow, d_fch[2*tt], d_fch[2*tt+1], r0, r1);
                d_fco[tt][0][j] = r0 + t_p2b[j];
                d_fco[tt][1][j] = r1 + t_p2b[j];
            }
        }
        __syncthreads();
        // ---- P7: q2 (ptr) — v20 verbatim ----
        {
            const float* col = ptr_W + (size_t)NH * NH + j;
            for (int tt = (tid >> 7); tt < CHc; tt += 2) {
                double qA0, qA1, qB0, qB1;
                qhalf(col, 0,  d_fco[tt][0], d_fco[tt][1], qA0, qA1);
                qhalf(col, 64, d_fco[tt][0], d_fco[tt][1], qB0, qB1);
                d_qh[tt][0][j] = dAbp[j] + (qA0 + qB0);
                d_qh[tt][1][j] = dAbp[j] + (qA1 + qB1);
            }
        }
        __syncthreads();
        // ---- P8: tanh heads — v20 verbatim ----
        for (int idx = tid; idx < 2 * CHc * NS; idx += NTHR) {
            int task = idx / NS, s = idx - task * NS;
            int tt = task >> 1, gg = task & 1;
            d_pl[task][s] = tanh_head(d_qh[tt][gg], dAp, t_vp, s_c0[gg][s], s_c1[gg][s]);
        }
        __syncthreads();
        // ---- P9: masked softmax2 + argmax + outputs — v20 verbatim ----
        {
            int w = tid >> 6;
            for (int task = w; task < 2 * CHc; task += 4) {
                int tt = task >> 1, gg = task & 1, tstep = t0 + tt;
                const unsigned* mwp = &maskb[tt][gg][0];
                bool u1 = (mwp[lane >> 5] >> (lane & 31)) & 1u;
                float l1 = d_pl[task][lane];
                float c1v = u1 ? l1 : NEGF;
                bool u2 = false; float l2 = 0.f, c2v = NEGF;
                if (lane + 64 < NS) {
                    u2 = (mwp[(lane + 64) >> 5] >> (lane & 31)) & 1u;
                    l2 = d_pl[task][lane + 64];
                    c2v = u2 ? l2 : NEGF;
                }
                float m = fmaxf(c1v, c2v);
                m = fmaxf(m, __shfl_xor(m, 32)); m = fmaxf(m, __shfl_xor(m, 16));
                m = fmaxf(m, __shfl_xor(m, 8));  m = fmaxf(m, __shfl_xor(m, 4));
                m = fmaxf(m, __shfl_xor(m, 2));  m = fmaxf(m, __shfl_xor(m, 1));
                float f1 = u1 ? (float)exp((double)l1 - (double)m) : 0.f;
                float f2 = (lane + 64 < NS && u2) ? (float)exp((double)l2 - (double)m) : 0.f;
                float bv = f1; int bi = lane;
                if (lane + 64 < NS && f2 > bv) { bv = f2; bi = lane + 64; }
                double ps = (double)f1 + (double)f2;
                #pragma unroll
                for (int o = 32; o >= 1; o >>= 1) {
                    float  ov = __shfl_xor(bv, o);
                    int    oi = __shfl_xor(bi, o);
                    double op = __shfl_xor(ps, o);
                    ps += op;
                    if (ov > bv || (ov == bv && oi < bi)) { bv = ov; bi = oi; }
                }
                int pt = s_sol2[gg][tstep];
                float a1s = __shfl(f1, pt & 63);
                float a2s = __shfl(f2, pt & 63);
                float a_pt = (pt < 64) ? a1s : a2s;
                if (lane == 0) {
                    int b2 = bbase + gg;
                    double logp = log((double)a_pt / ps);
                    out[OUT_TI + (size_t)b2 * NS + tstep]             = (float)bi;
                    out[OUT_LP + (size_t)b2 * (NS - 1) + (tstep - 1)] = (float)logp;
                }
            }
        }
        __syncthreads();
    }
}

extern "C" void kernel_launch(void* const* d_in, const int* in_sizes, int n_in,
                              void* d_out, int out_size, void* d_ws, size_t ws_size,
                              hipStream_t stream)
{
    (void)in_sizes; (void)n_in; (void)out_size; (void)d_ws; (void)ws_size;
    vae_v21<<<NBLK, NTHR, 0, stream>>>(
        (const float*)d_in[0], (const int*)d_in[1], (const int*)d_in[2], (const float*)d_in[3],
        (const float*)d_in[4], (const float*)d_in[5], (const float*)d_in[6], (const float*)d_in[7],
        (const float*)d_in[8], (const float*)d_in[9], (const float*)d_in[10], (const float*)d_in[11],
        (const float*)d_in[12], (const float*)d_in[13], (const float*)d_in[14], (const float*)d_in[15],
        (const float*)d_in[16], (const float*)d_in[17], (const float*)d_in[18], (const float*)d_in[19],
        (const float*)d_in[20], (const float*)d_in[21], (const float*)d_in[22], (const float*)d_in[23],
        (const float*)d_in[24], (const float*)d_in[25], (const float*)d_in[26], (const float*)d_in[27],
        (float*)d_out);
}